// Round 7
// baseline (770.113 us; speedup 1.0000x reference)
//
#include <hip/hip_runtime.h>
#include <hip/hip_bf16.h>
#include <math.h>

// Problem constants: B,L,D_MODEL=(2,4096,1024), D_INNER=2048, D_CONV=4
#define B_SZ 2
#define L_SZ 4096
#define DM   1024
#define DI   2048
#define E_SZ 4096
#define DC   4

typedef unsigned short u16;
typedef __attribute__((ext_vector_type(8))) short short8;   // 8 bf16 = 4 VGPRs
typedef __attribute__((ext_vector_type(4))) float f32x4;

__device__ __forceinline__ float silu_f(float v) {
    return v / (1.0f + __expf(-v));
}

// split fp32 -> bf16 hi (truncate) + bf16 lo (truncate of exact residual)
__device__ __forceinline__ void split_bf16(float x, u16& h, u16& l) {
    unsigned u  = __float_as_uint(x);
    unsigned hb = u & 0xFFFF0000u;
    h = (u16)(hb >> 16);
    float lf = x - __uint_as_float(hb);
    l = (u16)(__float_as_uint(lf) >> 16);
}
__device__ __forceinline__ float bf2f(u16 h) {
    return __uint_as_float(((unsigned)h) << 16);
}

// async global->LDS 16B: dest = wave-uniform LDS base + lane*16
__device__ __forceinline__ void gld_lds16(const u16* g, u16* l) {
    __builtin_amdgcn_global_load_lds(
        (const __attribute__((address_space(1))) unsigned int*)g,
        (__attribute__((address_space(3))) unsigned int*)l, 16, 0, 0);
}

__device__ __forceinline__ void mfma_triple(
    f32x4& acc, short8 ah, short8 al, short8 bh, short8 bl)
{
    acc = __builtin_amdgcn_mfma_f32_16x16x32_bf16(ah, bh, acc, 0, 0, 0);
    acc = __builtin_amdgcn_mfma_f32_16x16x32_bf16(ah, bl, acc, 0, 0, 0);
    acc = __builtin_amdgcn_mfma_f32_16x16x32_bf16(al, bh, acc, 0, 0, 0);
}

// build ah/al bf16x8 fragments from 8 interleaved (hi|lo) dwords
__device__ __forceinline__ void kperm(const unsigned* cur, short8& ah, short8& al) {
    union { unsigned u[4]; short8 s; } A_, B_;
    #pragma unroll
    for (int i = 0; i < 4; ++i) {
        A_.u[i] = __builtin_amdgcn_perm(cur[2*i+1], cur[2*i], 0x05040100u);
        B_.u[i] = __builtin_amdgcn_perm(cur[2*i+1], cur[2*i], 0x07060302u);
    }
    ah = A_.s; al = B_.s;
}
// prefetch k dwords for step c1 (indices provably >= 17 for c1 >= 1)
__device__ __forceinline__ void kpref(const unsigned* kp, int c1, unsigned* nxt) {
    #pragma unroll
    for (int e = 0; e < 8; ++e) nxt[e] = kp[32*c1 - e];
}

// ---------------------------------------------------------------------------
// pack_rm: fp32 row-major (R x K, k-contiguous, ldx) -> fragment-blocked split
// planes H/Lo laid out [K/32][R/16][512]; within a 16x32 block, element
// (m, k=8q+j) sits at (q*16+m)*8+j  == exactly the 16x16x32 MFMA frag order.
// ---------------------------------------------------------------------------
__global__ __launch_bounds__(256) void pack_rm(
    const float* __restrict__ X, u16* __restrict__ H, u16* __restrict__ Lo,
    int ldx, int r16n, long sX, long sOut)
{
    const long cid = (long)blockIdx.x * 256 + threadIdx.x;
    const int  qc  = (int)(cid & 63);
    const long blk = cid >> 6;
    const int  r16 = (int)(blk % r16n);
    const int  k32 = (int)(blk / r16n);
    const int  q = qc >> 4, m = qc & 15;

    const float* src = X + blockIdx.y * sX + (long)(r16 * 16 + m) * ldx + k32 * 32 + q * 8;
    float4 v0 = *(const float4*)src;
    float4 v1 = *(const float4*)(src + 4);
    float v[8] = {v0.x,v0.y,v0.z,v0.w,v1.x,v1.y,v1.z,v1.w};

    u16 hs[8], ls[8];
    #pragma unroll
    for (int j = 0; j < 8; ++j) split_bf16(v[j], hs[j], ls[j]);

    const long o = blockIdx.y * sOut + cid * 8;
    *(uint4*)&H[o]  = *(const uint4*)hs;
    *(uint4*)&Lo[o] = *(const uint4*)ls;
}

// ---------------------------------------------------------------------------
// MFMA split-bf16 GEMM (unchanged): 128x128 tile, BK=32, 4 waves.
// ---------------------------------------------------------------------------
__global__ __launch_bounds__(256) void gemm_mfma(
    const u16* __restrict__ Ah, const u16* __restrict__ Al,
    const u16* __restrict__ Bh, const u16* __restrict__ Bl,
    float* __restrict__ C,
    int r16A, int r16B, long sA, long sB, long sC,
    int ldc, int nk32)
{
    __shared__ alignas(16) u16 sm[4][4096];   // Ah,Al,Bh,Bl 128x32 tiles (8KB each)

    const int tid  = threadIdx.x;
    const int wv   = tid >> 6, lane = tid & 63;
    const long zb  = blockIdx.z;

    const u16* srcs0 = Ah + zb * sA;
    const u16* srcs1 = Al + zb * sA;
    const u16* srcs2 = Bh + zb * sB;
    const u16* srcs3 = Bl + zb * sB;
    const u16* mysrc = (wv == 0) ? srcs0 : (wv == 1) ? srcs1 : (wv == 2) ? srcs2 : srcs3;
    const int  rblk  = (wv < 2) ? blockIdx.x * 8 : blockIdx.y * 8;
    const int  r16c  = (wv < 2) ? r16A : r16B;
    u16* myl = sm[wv];

    const int wr = wv >> 1, wc = wv & 1;

    f32x4 acc[4][4];
    #pragma unroll
    for (int i = 0; i < 4; ++i)
        #pragma unroll
        for (int j = 0; j < 4; ++j)
            #pragma unroll
            for (int r = 0; r < 4; ++r) acc[i][j][r] = 0.f;

    for (int s = 0; s < nk32; ++s) {
        if (s) __syncthreads();
        {
            const u16* g = mysrc + (((long)s * r16c + rblk) << 9) + lane * 8;
            #pragma unroll
            for (int i = 0; i < 8; ++i)
                gld_lds16(g + (i << 9), myl + (i << 9));
        }
        __syncthreads();

        short8 afh[4], afl[4], bfh[4], bfl[4];
        const int aoff = (wr * 4) * 512 + lane * 8;
        const int boff = (wc * 4) * 512 + lane * 8;
        #pragma unroll
        for (int t = 0; t < 4; ++t) {
            afh[t] = *(const short8*)&sm[0][aoff + t * 512];
            afl[t] = *(const short8*)&sm[1][aoff + t * 512];
            bfh[t] = *(const short8*)&sm[2][boff + t * 512];
            bfl[t] = *(const short8*)&sm[3][boff + t * 512];
        }
        #pragma unroll
        for (int i = 0; i < 4; ++i)
            #pragma unroll
            for (int j = 0; j < 4; ++j) {
                acc[i][j] = __builtin_amdgcn_mfma_f32_16x16x32_bf16(afh[i], bfh[j], acc[i][j], 0, 0, 0);
                acc[i][j] = __builtin_amdgcn_mfma_f32_16x16x32_bf16(afh[i], bfl[j], acc[i][j], 0, 0, 0);
                acc[i][j] = __builtin_amdgcn_mfma_f32_16x16x32_bf16(afl[i], bfh[j], acc[i][j], 0, 0, 0);
            }
    }

    // C/D layout: col n = lane&15, row m = 4*(lane>>4)+reg
    const int m_ = lane & 15, q_ = lane >> 4;
    float* Cb = C + zb * sC;
    const int row00 = blockIdx.x * 128 + wr * 64 + q_ * 4;
    const int col0  = blockIdx.y * 128 + wc * 64 + m_;
    #pragma unroll
    for (int i = 0; i < 4; ++i)
        #pragma unroll
        for (int j = 0; j < 4; ++j) {
            const long base = (long)(row00 + i * 16) * ldc + col0 + j * 16;
            #pragma unroll
            for (int r = 0; r < 4; ++r)
                Cb[base + (long)r * ldc] = acc[i][j][r];
        }
}

// ---------------------------------------------------------------------------
// Depthwise causal conv4 + SiLU; emits x as split bf16 hi/lo planes (B,DI,L).
// ---------------------------------------------------------------------------
__global__ __launch_bounds__(256) void conv_silu_split(
    const float* __restrict__ xz, const float* __restrict__ conv_w,
    const float* __restrict__ conv_b,
    u16* __restrict__ xh_gl, u16* __restrict__ xl_gl)
{
    const long gid = (long)blockIdx.x * 256 + threadIdx.x;
    const int  q   = (int)(gid % (L_SZ / 4));
    const long bc  = gid / (L_SZ / 4);
    const int  ch  = (int)(bc % DI);
    const int  b   = (int)(bc / DI);

    const float* row = xz + ((long)b * E_SZ + ch) * L_SZ;
    const int l0 = q * 4;

    float4 cur  = *(const float4*)&row[l0];
    float4 prev = q ? *(const float4*)&row[l0 - 4] : make_float4(0.f, 0.f, 0.f, 0.f);

    const float w0 = conv_w[ch*DC+0], w1 = conv_w[ch*DC+1];
    const float w2 = conv_w[ch*DC+2], w3 = conv_w[ch*DC+3];
    const float bias = conv_b[ch];

    float o[4];
    o[0] = silu_f(bias + w0*prev.y + w1*prev.z + w2*prev.w + w3*cur.x);
    o[1] = silu_f(bias + w0*prev.z + w1*prev.w + w2*cur.x  + w3*cur.y);
    o[2] = silu_f(bias + w0*prev.w + w1*cur.x  + w2*cur.y  + w3*cur.z);
    o[3] = silu_f(bias + w0*cur.x  + w1*cur.y  + w2*cur.z  + w3*cur.w);

    unsigned long long hp = 0ull, lp = 0ull;
    #pragma unroll
    for (int r = 0; r < 4; ++r) {
        u16 h, l; split_bf16(o[r], h, l);
        hp |= ((unsigned long long)h) << (16*r);
        lp |= ((unsigned long long)l) << (16*r);
    }
    const long base = ((long)b * DI + ch) * L_SZ + l0;
    *(unsigned long long*)&xh_gl[base] = hp;
    *(unsigned long long*)&xl_gl[base] = lp;
}

// ---------------------------------------------------------------------------
// pack_k: k_ssm (DI, L) fp32 -> klv (DI, L) u32 with split-bf16 planes
// interleaved per element:  klv[i] = (u16)hi | ((u16)lo << 16).
// ---------------------------------------------------------------------------
__global__ __launch_bounds__(256) void pack_k(
    const float* __restrict__ k_ssm, unsigned* __restrict__ kv)
{
    const long gid = (long)blockIdx.x * 256 + threadIdx.x;   // DI*L/4 threads
    const int  qq  = (int)(gid & (L_SZ / 4 - 1));
    const int  ch  = (int)(gid >> 10);

    const long off = ((long)ch << 12) + qq * 4;
    float4 v = *(const float4*)&k_ssm[off];
    float f[4] = { v.x, v.y, v.z, v.w };
    unsigned o[4];
    #pragma unroll
    for (int r = 0; r < 4; ++r) {
        u16 h, l; split_bf16(f[r], h, l);
        o[r] = (unsigned)h | ((unsigned)l << 16);
    }
    *(uint4*)&kv[off] = *(const uint4*)o;
}

// ---------------------------------------------------------------------------
// MFMA long causal conv, R7: R2 body (proven 202.6us, VGPR 32) with the bl
// read stream moved LDS -> global.  R2 PMC: LDS-read pipe ~86% busy (2176
// ds_read_b128/ch) vs MFMA 52% -> LDS-throughput-bound.  bh is used in 2 of
// the 3 MFMAs, bl in 1.  Edits vs R2 (everything else byte-identical):
//  1. XL no longer staged to LDS (LDS 17.4KB -> 8.7KB, more blocks/CU)
//  2. bl = global_load_dwordx4 from xlr at gxb = xb - 256 (no pad in global);
//     per-lane mask (gxb<0 -> 0) replaces the LDS zero-pad.  gxb >= -240,
//     always within allocated memory (reads neighbors' tails, masked to 0).
//  3. __syncthreads() before epilogue: xlr now read from global throughout
//     the c-loop by all 4 waves, so the in-place y-write must wait for the
//     block-wide read drain.  (Per-wave epilogue regions are disjoint.)
//  4. epilogue reads the xl term from global instead of LDS.
// LDS reads: 2176 -> 1088 b128/ch (floor 418K -> 209K cyc/CU); bl stream
// rides the idle L1/L2 path (~48 B/cyc/CU, xl row is cache-resident).
// ---------------------------------------------------------------------------
__global__ __launch_bounds__(256, 6) void longconv_mfma(
    u16* __restrict__ xh_gl, u16* __restrict__ xl_gl,
    const float* __restrict__ xz,  const unsigned* __restrict__ kv,
    const float* __restrict__ D_skip)
{
    __shared__ alignas(16) u16 XH[4352];   // 256 zero-pad + 4096 (hi plane only)

    const int tid  = threadIdx.x;
    const int lane = tid & 63;
    const int wv   = tid >> 6;
    const int wc   = blockIdx.x;          // one channel per block
    const int ch   = wc & (DI - 1);
    const int b    = wc >> 11;

    u16*            xhr = xh_gl + ((long)b * DI + ch) * L_SZ;
    u16*            xlr = xl_gl + ((long)b * DI + ch) * L_SZ;
    const unsigned* kvr = kv + ((long)ch << 12);

    // zero the 512B pad of the hi plane (32 threads x 16B)
    if (tid < 32) {
        uint4 z = make_uint4(0u, 0u, 0u, 0u);
        ((uint4*)XH)[tid] = z;
    }
    // async stage 8KB hi plane: wave wv owns chunks {2wv, 2wv+1}
    {
        const int ck = wv * 2;
        gld_lds16(xhr + (ck    ) * 512 + lane * 8, XH + 256 + (ck    ) * 512);
        gld_lds16(xhr + (ck + 1) * 512 + lane * 8, XH + 256 + (ck + 1) * 512);
    }
    __syncthreads();

    const int m_ = lane & 15;
    const int q_ = lane >> 4;
    const int dq = m_ - 8 * q_ + ((q_ >= 2) ? 32 : 0);
    const int xoff_lane = 256 + 16 * m_ + 8 * q_ - ((q_ >= 2) ? 32 : 0);

    // balanced tile set for this wave: {w, 7-w, 8+w, 15-w}
    const int tset[4] = { wv, 7 - wv, 8 + wv, 15 - wv };
    const int tmax = 15 - wv;                 // largest tile owned
    const int cmax = 8 * tmax + 7;            // last c this wave needs

    f32x4 acc[4];
    #pragma unroll
    for (int u = 0; u < 4; ++u)
        #pragma unroll
        for (int r = 0; r < 4; ++r) acc[u][r] = 0.f;

    const unsigned* kp = kvr + dq;   // in-loop idx = 32*c1 + dq - e >= 17: safe

    unsigned lcur[8];
    #pragma unroll
    for (int e = 0; e < 8; ++e) {
        const int ki = dq - e;                        // -15..31: predicate once
        lcur[e] = (ki >= 0) ? kvr[ki] : 0u;
    }

    for (int c = 0; c <= cmax; ++c) {
        // assemble ah/al from interleaved dwords: 2 perms per pair
        short8 ah, al;
        kperm(lcur, ah, al);

        unsigned lnext[8];
        if (c < cmax) kpref(kp, c + 1, lnext);

        const int xb  = xoff_lane - 32 * c;           // LDS addr (hi, padded)
        const int xbg = xb - 256;                     // global addr (lo, no pad)
        #pragma unroll
        for (int u = 0; u < 4; ++u) {
            const int t = tset[u];
            if (8 * t >= c - 7) {
                const int g = xbg + 256 * t;          // in [-240, 4095], 16B-aligned
                uint4 blv = *(const uint4*)(xlr + g); // valid memory even when g<0
                if (g < 0) blv = make_uint4(0u, 0u, 0u, 0u);   // causal zero-pad
                union { uint4 uu; short8 ss; } cv; cv.uu = blv;
                short8 bh = *(const short8*)&XH[xb + 256 * t];
                mfma_triple(acc[u], ah, al, bh, cv.ss);
            }
        }

        if (c < cmax) {
            #pragma unroll
            for (int e = 0; e < 8; ++e) lcur[e] = lnext[e];
        }
    }

    // all waves must finish their global xlr reads before in-place y writes
    __syncthreads();

    // epilogue: y = (conv + D_skip*x) * silu(z)  -> split bf16, in-place rows
    const float  Ds   = D_skip[ch];
    const float* zrow = xz + ((long)b * E_SZ + DI + ch) * L_SZ;

    #pragma unroll
    for (int u = 0; u < 4; ++u) {
        const int t  = tset[u];
        const int l0 = 256 * t + 16 * m_ + 4 * q_;
        float4 zv = *(const float4*)&zrow[l0];
        float zt[4] = { zv.x, zv.y, zv.z, zv.w };
        const unsigned long long xlv = *(const unsigned long long*)&xlr[l0];
        unsigned long long hp = 0ull, lp = 0ull;
        #pragma unroll
        for (int r = 0; r < 4; ++r) {
            const float xf = bf2f(XH[256 + l0 + r])
                           + bf2f((u16)(xlv >> (16 * r)));
            const float o  = (acc[u][r] + Ds * xf) * silu_f(zt[r]);
            u16 h, l; split_bf16(o, h, l);
            hp |= ((unsigned long long)h) << (16*r);
            lp |= ((unsigned long long)l) << (16*r);
        }
        *(unsigned long long*)&xhr[l0] = hp;
        *(unsigned long long*)&xlr[l0] = lp;
    }
}

// ---------------------------------------------------------------------------
// pack_y: y split planes (B,DI,L) u16 -> GEMM2 A-operand fragment-blocked
// [K/32=64][L/16=256][512] per batch, via LDS transpose tile (32h x 128l).
// ---------------------------------------------------------------------------
__global__ __launch_bounds__(256) void pack_y(
    const u16* __restrict__ Yh, const u16* __restrict__ Yl,
    u16* __restrict__ OH, u16* __restrict__ OL, long sOut)
{
    __shared__ u16 T[2][32][136];
    const int t  = threadIdx.x;
    const int l0 = blockIdx.x * 128;
    const int h0 = blockIdx.y * 32;
    const int b  = blockIdx.z;

    const u16* yb_h = Yh + ((long)b * DI + h0) * L_SZ + l0;
    const u16* yb_l = Yl + ((long)b * DI + h0) * L_SZ + l0;

    #pragma unroll
    for (int i = 0; i < 2; ++i) {
        const int c = t + 256 * i;            // 0..511
        const int row = c >> 4, col = (c & 15) * 8;
        *(uint4*)&T[0][row][col] = *(const uint4*)&yb_h[(long)row * L_SZ + col];
        *(uint4*)&T[1][row][col] = *(const uint4*)&yb_l[(long)row * L_SZ + col];
    }
    __syncthreads();

    u16* outs[2] = { OH + b * sOut, OL + b * sOut };
    #pragma unroll
    for (int p = 0; p < 2; ++p) {
        #pragma unroll
        for (int i = 0; i < 2; ++i) {
            const int c = t + 256 * i;        // 0..511
            const int r16b = c >> 6, qc = c & 63;
            const int q = qc >> 4, m = qc & 15;
            const int l = r16b * 16 + m;
            u16 vals[8];
            #pragma unroll
            for (int j = 0; j < 8; ++j) vals[j] = T[p][q * 8 + j][l];
            const long o = ((long)(blockIdx.y * 256 + blockIdx.x * 8 + r16b) << 9) + qc * 8;
            *(uint4*)&outs[p][o] = *(const uint4*)vals;
        }
    }
}

// ---------------------------------------------------------------------------
extern "C" void kernel_launch(void* const* d_in, const int* in_sizes, int n_in,
                              void* d_out, int out_size, void* d_ws, size_t ws_size,
                              hipStream_t stream)
{
    const float* hidden = (const float*)d_in[0];  // (B, L, DM)
    const float* W_in   = (const float*)d_in[1];  // (E, DM)
    const float* conv_w = (const float*)d_in[2];  // (DI, 4)
    const float* conv_b = (const float*)d_in[3];  // (DI)
    const float* k_ssm  = (const float*)d_in[4];  // (DI, L)
    const float* D_skip = (const float*)d_in[5];  // (DI)
    const float* W_out  = (const float*)d_in[6];  // (DM, DI)
    float* out = (float*)d_out;                   // (B, L, DM)

    // ---- workspace layout (bytes) ----
    // xz fp32 (B,E,L)            @ 0          134,217,728
    //   klv u32 (DI,L) aliases xz x-half b=0 [0 .. 33,554,432) after conv
    // xh u16  (B,DI,L)           @ 134,217,728  33,554,432   (becomes y-hi)
    // xl u16  (B,DI,L)           @ 167,772,160  33,554,432   (becomes y-lo)
    // slotA: Win packs -> Wout packs @ 201,326,592  16,777,216
    // slotB: hidden packs        @ 218,103,808  33,554,432
    // yA packs alias xz x-halves (dead after longconv; overwrite klv too)
    char* ws = (char*)d_ws;
    float* xz  = (float*)ws;
    u16*   xh  = (u16*)(ws + 134217728);
    u16*   xl  = (u16*)(ws + 167772160);
    u16*   WinH  = (u16*)(ws + 201326592);
    u16*   WinL  = WinH + 4194304;            // 32*256*512
    u16*   WoutH = (u16*)(ws + 201326592);    // reused after GEMM1
    u16*   WoutL = WoutH + 2097152;           // 64*64*512
    u16*   hidH  = (u16*)(ws + 218103808);
    u16*   hidL  = hidH + 8388608;            // per-plane both batches
    unsigned* klv = (unsigned*)ws;            // aliases dead xz x-half b=0
    u16*   yAh   = (u16*)ws;                  // aliases xz; per-batch stride 33,554,432 elems
    u16*   yAl   = yAh + 8388608;

    // 1) pack W_in (R=E=4096,K=DM=1024) and hidden (per b: R=L,K=DM)
    pack_rm<<<dim3(2048, 1), 256, 0, stream>>>(W_in, WinH, WinL, DM, 256, 0L, 0L);
    pack_rm<<<dim3(2048, B_SZ), 256, 0, stream>>>(hidden, hidH, hidL, DM, 256,
        (long)L_SZ * DM, 4194304L);

    // 2) GEMM1: xz[b,e,l] = sum_d W_in[e,d]*hidden[b,l,d]
    gemm_mfma<<<dim3(32, 32, B_SZ), 256, 0, stream>>>(
        WinH, WinL, hidH, hidL, xz,
        256, 256, 0L, 4194304L, (long)E_SZ * L_SZ, L_SZ, 32);

    // 3) depthwise causal conv4 + SiLU -> split bf16 x
    conv_silu_split<<<dim3((unsigned)((long)B_SZ*DI*(L_SZ/4)/256)), 256, 0, stream>>>(
        xz, conv_w, conv_b, xh, xl);

    // 3b) pack k into interleaved split-bf16 dwords (xz x-half b0 now dead)
    pack_k<<<dim3((unsigned)((long)DI * (L_SZ/4) / 256)), 256, 0, stream>>>(k_ssm, klv);

    // 4) MFMA long causal conv + D_skip + silu(z) -> y split, in-place in xh/xl
    longconv_mfma<<<dim3(B_SZ * DI), 256, 0, stream>>>(
        xh, xl, xz, klv, D_skip);

    // 5) pack W_out (R=DM=1024,K=DI=2048) into slotA (Win packs now dead)
    pack_rm<<<dim3(1024, 1), 256, 0, stream>>>(W_out, WoutH, WoutL, DI, 64, 0L, 0L);

    // 6) pack y -> GEMM2 A-operand blocked (into dead xz x-half region)
    pack_y<<<dim3(32, 64, B_SZ), 256, 0, stream>>>(
        xh, xl, yAh, yAl, 33554432L);

    // 7) GEMM2: out[b,l,d] = sum_h y[b,h,l]*W_out[d,h]
    gemm_mfma<<<dim3(32, 8, B_SZ), 256, 0, stream>>>(
        yAh, yAl, WoutH, WoutL, out,
        256, 64, 33554432L, 0L, (long)L_SZ * DM, DM, 64);
}

// Round 8
// 654.297 us; speedup vs baseline: 1.1770x; 1.1770x over previous
//
#include <hip/hip_runtime.h>
#include <hip/hip_bf16.h>
#include <math.h>

// Problem constants: B,L,D_MODEL=(2,4096,1024), D_INNER=2048, D_CONV=4
#define B_SZ 2
#define L_SZ 4096
#define DM   1024
#define DI   2048
#define E_SZ 4096
#define DC   4

typedef unsigned short u16;
typedef __attribute__((ext_vector_type(8))) short short8;   // 8 bf16 = 4 VGPRs
typedef __attribute__((ext_vector_type(4))) float f32x4;

__device__ __forceinline__ float silu_f(float v) {
    return v / (1.0f + __expf(-v));
}

// split fp32 -> bf16 hi (truncate) + bf16 lo (truncate of exact residual)
__device__ __forceinline__ void split_bf16(float x, u16& h, u16& l) {
    unsigned u  = __float_as_uint(x);
    unsigned hb = u & 0xFFFF0000u;
    h = (u16)(hb >> 16);
    float lf = x - __uint_as_float(hb);
    l = (u16)(__float_as_uint(lf) >> 16);
}
__device__ __forceinline__ float bf2f(u16 h) {
    return __uint_as_float(((unsigned)h) << 16);
}

// async global->LDS 16B: dest = wave-uniform LDS base + lane*16
__device__ __forceinline__ void gld_lds16(const u16* g, u16* l) {
    __builtin_amdgcn_global_load_lds(
        (const __attribute__((address_space(1))) unsigned int*)g,
        (__attribute__((address_space(3))) unsigned int*)l, 16, 0, 0);
}

__device__ __forceinline__ void mfma_triple(
    f32x4& acc, short8 ah, short8 al, short8 bh, short8 bl)
{
    acc = __builtin_amdgcn_mfma_f32_16x16x32_bf16(ah, bh, acc, 0, 0, 0);
    acc = __builtin_amdgcn_mfma_f32_16x16x32_bf16(ah, bl, acc, 0, 0, 0);
    acc = __builtin_amdgcn_mfma_f32_16x16x32_bf16(al, bh, acc, 0, 0, 0);
}

// build ah/al bf16x8 fragments from 8 interleaved (hi|lo) dwords
__device__ __forceinline__ void kperm(const unsigned* cur, short8& ah, short8& al) {
    union { unsigned u[4]; short8 s; } A_, B_;
    #pragma unroll
    for (int i = 0; i < 4; ++i) {
        A_.u[i] = __builtin_amdgcn_perm(cur[2*i+1], cur[2*i], 0x05040100u);
        B_.u[i] = __builtin_amdgcn_perm(cur[2*i+1], cur[2*i], 0x07060302u);
    }
    ah = A_.s; al = B_.s;
}
// prefetch k dwords for step c1 (indices provably >= 17 for c1 >= 1)
__device__ __forceinline__ void kpref(const unsigned* kp, int c1, unsigned* nxt) {
    #pragma unroll
    for (int e = 0; e < 8; ++e) nxt[e] = kp[32*c1 - e];
}

// ---------------------------------------------------------------------------
// pack_rm: fp32 row-major (R x K, k-contiguous, ldx) -> fragment-blocked split
// planes H/Lo laid out [K/32][R/16][512]; within a 16x32 block, element
// (m, k=8q+j) sits at (q*16+m)*8+j  == exactly the 16x16x32 MFMA frag order.
// ---------------------------------------------------------------------------
__global__ __launch_bounds__(256) void pack_rm(
    const float* __restrict__ X, u16* __restrict__ H, u16* __restrict__ Lo,
    int ldx, int r16n, long sX, long sOut)
{
    const long cid = (long)blockIdx.x * 256 + threadIdx.x;
    const int  qc  = (int)(cid & 63);
    const long blk = cid >> 6;
    const int  r16 = (int)(blk % r16n);
    const int  k32 = (int)(blk / r16n);
    const int  q = qc >> 4, m = qc & 15;

    const float* src = X + blockIdx.y * sX + (long)(r16 * 16 + m) * ldx + k32 * 32 + q * 8;
    float4 v0 = *(const float4*)src;
    float4 v1 = *(const float4*)(src + 4);
    float v[8] = {v0.x,v0.y,v0.z,v0.w,v1.x,v1.y,v1.z,v1.w};

    u16 hs[8], ls[8];
    #pragma unroll
    for (int j = 0; j < 8; ++j) split_bf16(v[j], hs[j], ls[j]);

    const long o = blockIdx.y * sOut + cid * 8;
    *(uint4*)&H[o]  = *(const uint4*)hs;
    *(uint4*)&Lo[o] = *(const uint4*)ls;
}

// ---------------------------------------------------------------------------
// MFMA split-bf16 GEMM: 128x128 tile, BK=32, 4 waves.  R8: bijective
// XCD-aware block swizzle (T1, m204 form) -- per-z nwg is 1024 (GEMM1) or
// 256 (GEMM2), both %8==0, so the simple chunked remap is bijective.
// Blocks sharing operand panels cluster on one XCD's L2.
// ---------------------------------------------------------------------------
__global__ __launch_bounds__(256) void gemm_mfma(
    const u16* __restrict__ Ah, const u16* __restrict__ Al,
    const u16* __restrict__ Bh, const u16* __restrict__ Bl,
    float* __restrict__ C,
    int r16A, int r16B, long sA, long sB, long sC,
    int ldc, int nk32)
{
    __shared__ alignas(16) u16 sm[4][4096];   // Ah,Al,Bh,Bl 128x32 tiles (8KB each)

    const int tid  = threadIdx.x;
    const int wv   = tid >> 6, lane = tid & 63;
    const long zb  = blockIdx.z;

    // XCD swizzle (per-z): contiguous chunk of flat ids per XCD
    const int nbx = gridDim.x;
    const int nwg = gridDim.x * gridDim.y;     // 1024 or 256: %8 == 0
    int flat = blockIdx.x + nbx * blockIdx.y;
    const int cpx = nwg >> 3;
    flat = (flat & 7) * cpx + (flat >> 3);
    const int bx = flat % nbx, by = flat / nbx;

    const u16* srcs0 = Ah + zb * sA;
    const u16* srcs1 = Al + zb * sA;
    const u16* srcs2 = Bh + zb * sB;
    const u16* srcs3 = Bl + zb * sB;
    const u16* mysrc = (wv == 0) ? srcs0 : (wv == 1) ? srcs1 : (wv == 2) ? srcs2 : srcs3;
    const int  rblk  = (wv < 2) ? bx * 8 : by * 8;
    const int  r16c  = (wv < 2) ? r16A : r16B;
    u16* myl = sm[wv];

    const int wr = wv >> 1, wc = wv & 1;

    f32x4 acc[4][4];
    #pragma unroll
    for (int i = 0; i < 4; ++i)
        #pragma unroll
        for (int j = 0; j < 4; ++j)
            #pragma unroll
            for (int r = 0; r < 4; ++r) acc[i][j][r] = 0.f;

    for (int s = 0; s < nk32; ++s) {
        if (s) __syncthreads();
        {
            const u16* g = mysrc + (((long)s * r16c + rblk) << 9) + lane * 8;
            #pragma unroll
            for (int i = 0; i < 8; ++i)
                gld_lds16(g + (i << 9), myl + (i << 9));
        }
        __syncthreads();

        short8 afh[4], afl[4], bfh[4], bfl[4];
        const int aoff = (wr * 4) * 512 + lane * 8;
        const int boff = (wc * 4) * 512 + lane * 8;
        #pragma unroll
        for (int t = 0; t < 4; ++t) {
            afh[t] = *(const short8*)&sm[0][aoff + t * 512];
            afl[t] = *(const short8*)&sm[1][aoff + t * 512];
            bfh[t] = *(const short8*)&sm[2][boff + t * 512];
            bfl[t] = *(const short8*)&sm[3][boff + t * 512];
        }
        #pragma unroll
        for (int i = 0; i < 4; ++i)
            #pragma unroll
            for (int j = 0; j < 4; ++j) {
                acc[i][j] = __builtin_amdgcn_mfma_f32_16x16x32_bf16(afh[i], bfh[j], acc[i][j], 0, 0, 0);
                acc[i][j] = __builtin_amdgcn_mfma_f32_16x16x32_bf16(afh[i], bfl[j], acc[i][j], 0, 0, 0);
                acc[i][j] = __builtin_amdgcn_mfma_f32_16x16x32_bf16(afl[i], bfh[j], acc[i][j], 0, 0, 0);
            }
    }

    // C/D layout: col n = lane&15, row m = 4*(lane>>4)+reg
    const int m_ = lane & 15, q_ = lane >> 4;
    float* Cb = C + zb * sC;
    const int row00 = bx * 128 + wr * 64 + q_ * 4;
    const int col0  = by * 128 + wc * 64 + m_;
    #pragma unroll
    for (int i = 0; i < 4; ++i)
        #pragma unroll
        for (int j = 0; j < 4; ++j) {
            const long base = (long)(row00 + i * 16) * ldc + col0 + j * 16;
            #pragma unroll
            for (int r = 0; r < 4; ++r)
                Cb[base + (long)r * ldc] = acc[i][j][r];
        }
}

// ---------------------------------------------------------------------------
// Depthwise causal conv4 + SiLU; emits x as split bf16 hi/lo planes (B,DI,L).
// ---------------------------------------------------------------------------
__global__ __launch_bounds__(256) void conv_silu_split(
    const float* __restrict__ xz, const float* __restrict__ conv_w,
    const float* __restrict__ conv_b,
    u16* __restrict__ xh_gl, u16* __restrict__ xl_gl)
{
    const long gid = (long)blockIdx.x * 256 + threadIdx.x;
    const int  q   = (int)(gid % (L_SZ / 4));
    const long bc  = gid / (L_SZ / 4);
    const int  ch  = (int)(bc % DI);
    const int  b   = (int)(bc / DI);

    const float* row = xz + ((long)b * E_SZ + ch) * L_SZ;
    const int l0 = q * 4;

    float4 cur  = *(const float4*)&row[l0];
    float4 prev = q ? *(const float4*)&row[l0 - 4] : make_float4(0.f, 0.f, 0.f, 0.f);

    const float w0 = conv_w[ch*DC+0], w1 = conv_w[ch*DC+1];
    const float w2 = conv_w[ch*DC+2], w3 = conv_w[ch*DC+3];
    const float bias = conv_b[ch];

    float o[4];
    o[0] = silu_f(bias + w0*prev.y + w1*prev.z + w2*prev.w + w3*cur.x);
    o[1] = silu_f(bias + w0*prev.z + w1*prev.w + w2*cur.x  + w3*cur.y);
    o[2] = silu_f(bias + w0*prev.w + w1*cur.x  + w2*cur.y  + w3*cur.z);
    o[3] = silu_f(bias + w0*cur.x  + w1*cur.y  + w2*cur.z  + w3*cur.w);

    unsigned long long hp = 0ull, lp = 0ull;
    #pragma unroll
    for (int r = 0; r < 4; ++r) {
        u16 h, l; split_bf16(o[r], h, l);
        hp |= ((unsigned long long)h) << (16*r);
        lp |= ((unsigned long long)l) << (16*r);
    }
    const long base = ((long)b * DI + ch) * L_SZ + l0;
    *(unsigned long long*)&xh_gl[base] = hp;
    *(unsigned long long*)&xl_gl[base] = lp;
}

// ---------------------------------------------------------------------------
// pack_k: k_ssm (DI, L) fp32 -> klv (DI, L) u32 with split-bf16 planes
// interleaved per element:  klv[i] = (u16)hi | ((u16)lo << 16).
// ---------------------------------------------------------------------------
__global__ __launch_bounds__(256) void pack_k(
    const float* __restrict__ k_ssm, unsigned* __restrict__ kv)
{
    const long gid = (long)blockIdx.x * 256 + threadIdx.x;   // DI*L/4 threads
    const int  qq  = (int)(gid & (L_SZ / 4 - 1));
    const int  ch  = (int)(gid >> 10);

    const long off = ((long)ch << 12) + qq * 4;
    float4 v = *(const float4*)&k_ssm[off];
    float f[4] = { v.x, v.y, v.z, v.w };
    unsigned o[4];
    #pragma unroll
    for (int r = 0; r < 4; ++r) {
        u16 h, l; split_bf16(f[r], h, l);
        o[r] = (unsigned)h | ((unsigned)l << 16);
    }
    *(uint4*)&kv[off] = *(const uint4*)o;
}

// ---------------------------------------------------------------------------
// MFMA long causal conv -- FROZEN R2 body (202.6us, VGPR 32, occupancy 70%,
// zero spill).  Five structural variants refuted on counters:
//  R3/R4 reg-ring: spilled under launch_bounds VGPR brackets (+550/77MB HBM)
//  R5 ring @ (256,1): clean regs but 21% occupancy -> latency-bound (325us)
//  R6 segmented guard-free loop: regalloc perturbation, minor spill (231us)
//  R7 bl via global: per-lane L2-latency on critical path (375us)
// Do not modify without new counter evidence.
// 1 channel / 256-thr block, 4 waves share one LDS X image; tiles split
// {w, 7-w, 8+w, 15-w} (272 MFMA-triples/wave); k pre-split (pack_k), 8
// v_perm_b32/step fragment assembly; async global_load_lds staging.
// ---------------------------------------------------------------------------
__global__ __launch_bounds__(256, 6) void longconv_mfma(
    u16* __restrict__ xh_gl, u16* __restrict__ xl_gl,
    const float* __restrict__ xz,  const unsigned* __restrict__ kv,
    const float* __restrict__ D_skip)
{
    __shared__ alignas(16) u16 XH[4352];   // 256 zero-pad + 4096
    __shared__ alignas(16) u16 XL[4352];

    const int tid  = threadIdx.x;
    const int lane = tid & 63;
    const int wv   = tid >> 6;
    const int wc   = blockIdx.x;          // one channel per block
    const int ch   = wc & (DI - 1);
    const int b    = wc >> 11;

    u16*            xhr = xh_gl + ((long)b * DI + ch) * L_SZ;
    u16*            xlr = xl_gl + ((long)b * DI + ch) * L_SZ;
    const unsigned* kvr = kv + ((long)ch << 12);

    // zero the 512B pad of each plane (64 threads x 16B)
    if (tid < 64) {
        uint4 z = make_uint4(0u, 0u, 0u, 0u);
        ((uint4*)((tid < 32) ? XH : XL))[tid & 31] = z;
    }
    // async stage 8KB/plane: wave wv owns chunks {2wv, 2wv+1} of each plane
    {
        const int ck = wv * 2;
        gld_lds16(xhr + (ck    ) * 512 + lane * 8, XH + 256 + (ck    ) * 512);
        gld_lds16(xhr + (ck + 1) * 512 + lane * 8, XH + 256 + (ck + 1) * 512);
        gld_lds16(xlr + (ck    ) * 512 + lane * 8, XL + 256 + (ck    ) * 512);
        gld_lds16(xlr + (ck + 1) * 512 + lane * 8, XL + 256 + (ck + 1) * 512);
    }
    __syncthreads();

    const int m_ = lane & 15;
    const int q_ = lane >> 4;
    const int dq = m_ - 8 * q_ + ((q_ >= 2) ? 32 : 0);
    const int xoff_lane = 256 + 16 * m_ + 8 * q_ - ((q_ >= 2) ? 32 : 0);

    // balanced tile set for this wave: {w, 7-w, 8+w, 15-w}
    const int tset[4] = { wv, 7 - wv, 8 + wv, 15 - wv };
    const int tmax = 15 - wv;                 // largest tile owned
    const int cmax = 8 * tmax + 7;            // last c this wave needs

    f32x4 acc[4];
    #pragma unroll
    for (int u = 0; u < 4; ++u)
        #pragma unroll
        for (int r = 0; r < 4; ++r) acc[u][r] = 0.f;

    const unsigned* kp = kvr + dq;   // in-loop idx = 32*c1 + dq - e >= 17: safe

    unsigned lcur[8];
    #pragma unroll
    for (int e = 0; e < 8; ++e) {
        const int ki = dq - e;                        // -15..31: predicate once
        lcur[e] = (ki >= 0) ? kvr[ki] : 0u;
    }

    for (int c = 0; c <= cmax; ++c) {
        // assemble ah/al from interleaved dwords: 2 perms per pair
        short8 ah, al;
        kperm(lcur, ah, al);

        unsigned lnext[8];
        if (c < cmax) kpref(kp, c + 1, lnext);

        const int xbase = xoff_lane - 32 * c;
        #pragma unroll
        for (int u = 0; u < 4; ++u) {
            const int t = tset[u];
            if (8 * t >= c - 7) {
                short8 bh = *(const short8*)&XH[xbase + 256 * t];
                short8 bl = *(const short8*)&XL[xbase + 256 * t];
                acc[u] = __builtin_amdgcn_mfma_f32_16x16x32_bf16(ah, bh, acc[u], 0, 0, 0);
                acc[u] = __builtin_amdgcn_mfma_f32_16x16x32_bf16(ah, bl, acc[u], 0, 0, 0);
                acc[u] = __builtin_amdgcn_mfma_f32_16x16x32_bf16(al, bh, acc[u], 0, 0, 0);
            }
        }

        if (c < cmax) {
            #pragma unroll
            for (int e = 0; e < 8; ++e) lcur[e] = lnext[e];
        }
    }

    // epilogue: y = (conv + D_skip*x) * silu(z)  -> split bf16, in-place rows
    const float  Ds   = D_skip[ch];
    const float* zrow = xz + ((long)b * E_SZ + DI + ch) * L_SZ;

    #pragma unroll
    for (int u = 0; u < 4; ++u) {
        const int t  = tset[u];
        const int l0 = 256 * t + 16 * m_ + 4 * q_;
        float4 zv = *(const float4*)&zrow[l0];
        float zt[4] = { zv.x, zv.y, zv.z, zv.w };
        unsigned long long hp = 0ull, lp = 0ull;
        #pragma unroll
        for (int r = 0; r < 4; ++r) {
            const float xf = bf2f(XH[256 + l0 + r]) + bf2f(XL[256 + l0 + r]);
            const float o  = (acc[u][r] + Ds * xf) * silu_f(zt[r]);
            u16 h, l; split_bf16(o, h, l);
            hp |= ((unsigned long long)h) << (16*r);
            lp |= ((unsigned long long)l) << (16*r);
        }
        *(unsigned long long*)&xhr[l0] = hp;
        *(unsigned long long*)&xlr[l0] = lp;
    }
}

// ---------------------------------------------------------------------------
// pack_y: y split planes (B,DI,L) u16 -> GEMM2 A-operand fragment-blocked
// [K/32=64][L/16=256][512] per batch, via LDS transpose tile (32h x 128l).
// ---------------------------------------------------------------------------
__global__ __launch_bounds__(256) void pack_y(
    const u16* __restrict__ Yh, const u16* __restrict__ Yl,
    u16* __restrict__ OH, u16* __restrict__ OL, long sOut)
{
    __shared__ u16 T[2][32][136];
    const int t  = threadIdx.x;
    const int l0 = blockIdx.x * 128;
    const int h0 = blockIdx.y * 32;
    const int b  = blockIdx.z;

    const u16* yb_h = Yh + ((long)b * DI + h0) * L_SZ + l0;
    const u16* yb_l = Yl + ((long)b * DI + h0) * L_SZ + l0;

    #pragma unroll
    for (int i = 0; i < 2; ++i) {
        const int c = t + 256 * i;            // 0..511
        const int row = c >> 4, col = (c & 15) * 8;
        *(uint4*)&T[0][row][col] = *(const uint4*)&yb_h[(long)row * L_SZ + col];
        *(uint4*)&T[1][row][col] = *(const uint4*)&yb_l[(long)row * L_SZ + col];
    }
    __syncthreads();

    u16* outs[2] = { OH + b * sOut, OL + b * sOut };
    #pragma unroll
    for (int p = 0; p < 2; ++p) {
        #pragma unroll
        for (int i = 0; i < 2; ++i) {
            const int c = t + 256 * i;        // 0..511
            const int r16b = c >> 6, qc = c & 63;
            const int q = qc >> 4, m = qc & 15;
            const int l = r16b * 16 + m;
            u16 vals[8];
            #pragma unroll
            for (int j = 0; j < 8; ++j) vals[j] = T[p][q * 8 + j][l];
            const long o = ((long)(blockIdx.y * 256 + blockIdx.x * 8 + r16b) << 9) + qc * 8;
            *(uint4*)&outs[p][o] = *(const uint4*)vals;
        }
    }
}

// ---------------------------------------------------------------------------
extern "C" void kernel_launch(void* const* d_in, const int* in_sizes, int n_in,
                              void* d_out, int out_size, void* d_ws, size_t ws_size,
                              hipStream_t stream)
{
    const float* hidden = (const float*)d_in[0];  // (B, L, DM)
    const float* W_in   = (const float*)d_in[1];  // (E, DM)
    const float* conv_w = (const float*)d_in[2];  // (DI, 4)
    const float* conv_b = (const float*)d_in[3];  // (DI)
    const float* k_ssm  = (const float*)d_in[4];  // (DI, L)
    const float* D_skip = (const float*)d_in[5];  // (DI)
    const float* W_out  = (const float*)d_in[6];  // (DM, DI)
    float* out = (float*)d_out;                   // (B, L, DM)

    // ---- workspace layout (bytes) ----
    // xz fp32 (B,E,L)            @ 0          134,217,728
    //   klv u32 (DI,L) aliases xz x-half b=0 [0 .. 33,554,432) after conv
    // xh u16  (B,DI,L)           @ 134,217,728  33,554,432   (becomes y-hi)
    // xl u16  (B,DI,L)           @ 167,772,160  33,554,432   (becomes y-lo)
    // slotA: Win packs -> Wout packs @ 201,326,592  16,777,216
    // slotB: hidden packs        @ 218,103,808  33,554,432
    // yA packs alias xz x-halves (dead after longconv; overwrite klv too)
    char* ws = (char*)d_ws;
    float* xz  = (float*)ws;
    u16*   xh  = (u16*)(ws + 134217728);
    u16*   xl  = (u16*)(ws + 167772160);
    u16*   WinH  = (u16*)(ws + 201326592);
    u16*   WinL  = WinH + 4194304;            // 32*256*512
    u16*   WoutH = (u16*)(ws + 201326592);    // reused after GEMM1
    u16*   WoutL = WoutH + 2097152;           // 64*64*512
    u16*   hidH  = (u16*)(ws + 218103808);
    u16*   hidL  = hidH + 8388608;            // per-plane both batches
    unsigned* klv = (unsigned*)ws;            // aliases dead xz x-half b=0
    u16*   yAh   = (u16*)ws;                  // aliases xz; per-batch stride 33,554,432 elems
    u16*   yAl   = yAh + 8388608;

    // 1) pack W_in (R=E=4096,K=DM=1024) and hidden (per b: R=L,K=DM)
    pack_rm<<<dim3(2048, 1), 256, 0, stream>>>(W_in, WinH, WinL, DM, 256, 0L, 0L);
    pack_rm<<<dim3(2048, B_SZ), 256, 0, stream>>>(hidden, hidH, hidL, DM, 256,
        (long)L_SZ * DM, 4194304L);

    // 2) GEMM1: xz[b,e,l] = sum_d W_in[e,d]*hidden[b,l,d]
    gemm_mfma<<<dim3(32, 32, B_SZ), 256, 0, stream>>>(
        WinH, WinL, hidH, hidL, xz,
        256, 256, 0L, 4194304L, (long)E_SZ * L_SZ, L_SZ, 32);

    // 3) depthwise causal conv4 + SiLU -> split bf16 x
    conv_silu_split<<<dim3((unsigned)((long)B_SZ*DI*(L_SZ/4)/256)), 256, 0, stream>>>(
        xz, conv_w, conv_b, xh, xl);

    // 3b) pack k into interleaved split-bf16 dwords (xz x-half b0 now dead)
    pack_k<<<dim3((unsigned)((long)DI * (L_SZ/4) / 256)), 256, 0, stream>>>(k_ssm, klv);

    // 4) MFMA long causal conv + D_skip + silu(z) -> y split, in-place in xh/xl
    longconv_mfma<<<dim3(B_SZ * DI), 256, 0, stream>>>(
        xh, xl, xz, klv, D_skip);

    // 5) pack W_out (R=DM=1024,K=DI=2048) into slotA (Win packs now dead)
    pack_rm<<<dim3(1024, 1), 256, 0, stream>>>(W_out, WoutH, WoutL, DI, 64, 0L, 0L);

    // 6) pack y -> GEMM2 A-operand blocked (into dead xz x-half region)
    pack_y<<<dim3(32, 64, B_SZ), 256, 0, stream>>>(
        xh, xl, yAh, yAl, 33554432L);

    // 7) GEMM2: out[b,l,d] = sum_h y[b,h,l]*W_out[d,h]
    gemm_mfma<<<dim3(32, 8, B_SZ), 256, 0, stream>>>(
        yAh, yAl, WoutH, WoutL, out,
        256, 64, 33554432L, 0L, (long)L_SZ * DM, DM, 64);
}

// Round 9
// 625.825 us; speedup vs baseline: 1.2306x; 1.0455x over previous
//
#include <hip/hip_runtime.h>
#include <hip/hip_bf16.h>
#include <math.h>

// Problem constants: B,L,D_MODEL=(2,4096,1024), D_INNER=2048, D_CONV=4
#define B_SZ 2
#define L_SZ 4096
#define DM   1024
#define DI   2048
#define E_SZ 4096
#define DC   4

typedef unsigned short u16;
typedef __attribute__((ext_vector_type(8))) short short8;   // 8 bf16 = 4 VGPRs
typedef __attribute__((ext_vector_type(4))) float f32x4;

__device__ __forceinline__ float silu_f(float v) {
    return v / (1.0f + __expf(-v));
}

// split fp32 -> bf16 hi (truncate) + bf16 lo (truncate of exact residual)
__device__ __forceinline__ void split_bf16(float x, u16& h, u16& l) {
    unsigned u  = __float_as_uint(x);
    unsigned hb = u & 0xFFFF0000u;
    h = (u16)(hb >> 16);
    float lf = x - __uint_as_float(hb);
    l = (u16)(__float_as_uint(lf) >> 16);
}
__device__ __forceinline__ float bf2f(u16 h) {
    return __uint_as_float(((unsigned)h) << 16);
}

// async global->LDS 16B: dest = wave-uniform LDS base + lane*16
__device__ __forceinline__ void gld_lds16(const u16* g, u16* l) {
    __builtin_amdgcn_global_load_lds(
        (const __attribute__((address_space(1))) unsigned int*)g,
        (__attribute__((address_space(3))) unsigned int*)l, 16, 0, 0);
}

__device__ __forceinline__ void mfma_triple(
    f32x4& acc, short8 ah, short8 al, short8 bh, short8 bl)
{
    acc = __builtin_amdgcn_mfma_f32_16x16x32_bf16(ah, bh, acc, 0, 0, 0);
    acc = __builtin_amdgcn_mfma_f32_16x16x32_bf16(ah, bl, acc, 0, 0, 0);
    acc = __builtin_amdgcn_mfma_f32_16x16x32_bf16(al, bh, acc, 0, 0, 0);
}

// build ah/al bf16x8 fragments from 8 interleaved (hi|lo) dwords
__device__ __forceinline__ void kperm(const unsigned* cur, short8& ah, short8& al) {
    union { unsigned u[4]; short8 s; } A_, B_;
    #pragma unroll
    for (int i = 0; i < 4; ++i) {
        A_.u[i] = __builtin_amdgcn_perm(cur[2*i+1], cur[2*i], 0x05040100u);
        B_.u[i] = __builtin_amdgcn_perm(cur[2*i+1], cur[2*i], 0x07060302u);
    }
    ah = A_.s; al = B_.s;
}
// prefetch k dwords for step c1 (indices provably >= 17 for c1 >= 1)
__device__ __forceinline__ void kpref(const unsigned* kp, int c1, unsigned* nxt) {
    #pragma unroll
    for (int e = 0; e < 8; ++e) nxt[e] = kp[32*c1 - e];
}

// ---------------------------------------------------------------------------
// pack_rm: fp32 row-major (R x K, k-contiguous, ldx) -> fragment-blocked split
// planes H/Lo laid out [K/32][R/16][512]; within a 16x32 block, element
// (m, k=8q+j) sits at (q*16+m)*8+j  == exactly the 16x16x32 MFMA frag order.
// ---------------------------------------------------------------------------
__global__ __launch_bounds__(256) void pack_rm(
    const float* __restrict__ X, u16* __restrict__ H, u16* __restrict__ Lo,
    int ldx, int r16n, long sX, long sOut)
{
    const long cid = (long)blockIdx.x * 256 + threadIdx.x;
    const int  qc  = (int)(cid & 63);
    const long blk = cid >> 6;
    const int  r16 = (int)(blk % r16n);
    const int  k32 = (int)(blk / r16n);
    const int  q = qc >> 4, m = qc & 15;

    const float* src = X + blockIdx.y * sX + (long)(r16 * 16 + m) * ldx + k32 * 32 + q * 8;
    float4 v0 = *(const float4*)src;
    float4 v1 = *(const float4*)(src + 4);
    float v[8] = {v0.x,v0.y,v0.z,v0.w,v1.x,v1.y,v1.z,v1.w};

    u16 hs[8], ls[8];
    #pragma unroll
    for (int j = 0; j < 8; ++j) split_bf16(v[j], hs[j], ls[j]);

    const long o = blockIdx.y * sOut + cid * 8;
    *(uint4*)&H[o]  = *(const uint4*)hs;
    *(uint4*)&Lo[o] = *(const uint4*)ls;
}

// ---------------------------------------------------------------------------
// MFMA split-bf16 GEMM, R2-exact (no swizzle): 128x128 tile, BK=32, 4 waves.
// Used for GEMM2 (N=1024 -> 256^2 tile would leave half the CUs idle).
// ---------------------------------------------------------------------------
__global__ __launch_bounds__(256) void gemm_mfma(
    const u16* __restrict__ Ah, const u16* __restrict__ Al,
    const u16* __restrict__ Bh, const u16* __restrict__ Bl,
    float* __restrict__ C,
    int r16A, int r16B, long sA, long sB, long sC,
    int ldc, int nk32)
{
    __shared__ alignas(16) u16 sm[4][4096];   // Ah,Al,Bh,Bl 128x32 tiles (8KB each)

    const int tid  = threadIdx.x;
    const int wv   = tid >> 6, lane = tid & 63;
    const long zb  = blockIdx.z;

    const u16* srcs0 = Ah + zb * sA;
    const u16* srcs1 = Al + zb * sA;
    const u16* srcs2 = Bh + zb * sB;
    const u16* srcs3 = Bl + zb * sB;
    const u16* mysrc = (wv == 0) ? srcs0 : (wv == 1) ? srcs1 : (wv == 2) ? srcs2 : srcs3;
    const int  rblk  = (wv < 2) ? blockIdx.x * 8 : blockIdx.y * 8;
    const int  r16c  = (wv < 2) ? r16A : r16B;
    u16* myl = sm[wv];

    const int wr = wv >> 1, wc = wv & 1;

    f32x4 acc[4][4];
    #pragma unroll
    for (int i = 0; i < 4; ++i)
        #pragma unroll
        for (int j = 0; j < 4; ++j)
            #pragma unroll
            for (int r = 0; r < 4; ++r) acc[i][j][r] = 0.f;

    for (int s = 0; s < nk32; ++s) {
        if (s) __syncthreads();
        {
            const u16* g = mysrc + (((long)s * r16c + rblk) << 9) + lane * 8;
            #pragma unroll
            for (int i = 0; i < 8; ++i)
                gld_lds16(g + (i << 9), myl + (i << 9));
        }
        __syncthreads();

        short8 afh[4], afl[4], bfh[4], bfl[4];
        const int aoff = (wr * 4) * 512 + lane * 8;
        const int boff = (wc * 4) * 512 + lane * 8;
        #pragma unroll
        for (int t = 0; t < 4; ++t) {
            afh[t] = *(const short8*)&sm[0][aoff + t * 512];
            afl[t] = *(const short8*)&sm[1][aoff + t * 512];
            bfh[t] = *(const short8*)&sm[2][boff + t * 512];
            bfl[t] = *(const short8*)&sm[3][boff + t * 512];
        }
        #pragma unroll
        for (int i = 0; i < 4; ++i)
            #pragma unroll
            for (int j = 0; j < 4; ++j) {
                acc[i][j] = __builtin_amdgcn_mfma_f32_16x16x32_bf16(afh[i], bfh[j], acc[i][j], 0, 0, 0);
                acc[i][j] = __builtin_amdgcn_mfma_f32_16x16x32_bf16(afh[i], bfl[j], acc[i][j], 0, 0, 0);
                acc[i][j] = __builtin_amdgcn_mfma_f32_16x16x32_bf16(afl[i], bfh[j], acc[i][j], 0, 0, 0);
            }
    }

    // C/D layout: col n = lane&15, row m = 4*(lane>>4)+reg
    const int m_ = lane & 15, q_ = lane >> 4;
    float* Cb = C + zb * sC;
    const int row00 = blockIdx.x * 128 + wr * 64 + q_ * 4;
    const int col0  = blockIdx.y * 128 + wc * 64 + m_;
    #pragma unroll
    for (int i = 0; i < 4; ++i)
        #pragma unroll
        for (int j = 0; j < 4; ++j) {
            const long base = (long)(row00 + i * 16) * ldc + col0 + j * 16;
            #pragma unroll
            for (int r = 0; r < 4; ++r)
                Cb[base + (long)r * ldc] = acc[i][j][r];
        }
}

// ---------------------------------------------------------------------------
// gemm256: 256x256 tile, BK=32, 512 thr = 8 waves (2M x 4N), double-buffered
// 128KB LDS, T3-lite pipeline: ONE __syncthreads per K-step, next-tile
// global_load_lds issued immediately AFTER the barrier so HBM/L2 latency
// hides under the full K-step of MFMA (96/wave).  Evidence: 128^2 structure
// ceilings at ~900TF regardless of pipelining (m99-m141, m232); 256^2 with
// post-barrier staging is the proven escape (learn_hip T3, m230/m248).
// Operands pre-packed fragment-blocked -> ds_reads lane-linear (no swizzle
// needed, T2 satisfied by construction).
// LDS buffer layout: [64 blocks][512]: 0-15 AH r16, 16-31 AL, 32-47 BH,
// 48-63 BL.  Wave wv stages blocks [wv*8, wv*8+8) (plane wv>>1).
// launch_bounds(512,1): leave allocator uncapped (R3-R5 bracket evidence);
// kernel needs ~220 VGPR (acc 8x4 f32x4 = 128) -> 2 waves/SIMD naturally.
// ---------------------------------------------------------------------------
__global__ __launch_bounds__(512, 1) void gemm256(
    const u16* __restrict__ Ah, const u16* __restrict__ Al,
    const u16* __restrict__ Bh, const u16* __restrict__ Bl,
    float* __restrict__ C,
    int r16A, int r16B, long sA, long sB, long sC,
    int ldc, int nk32)
{
    __shared__ alignas(16) u16 sm[2][64][512];   // 128 KB

    const int tid  = threadIdx.x;
    const int wv   = tid >> 6, lane = tid & 63;
    const long zb  = blockIdx.z;
    const int bx = blockIdx.x, by = blockIdx.y;

    const int wr  = wv >> 2;        // 0..1  M-half (128 rows)
    const int wcn = wv & 3;         // 0..3  N-quarter (64 cols)

    // staging role: plane pidx = wv>>1; 8 r16-blocks starting at rbase
    const u16* planes0 = Ah + zb * sA;
    const u16* planes1 = Al + zb * sA;
    const u16* planes2 = Bh + zb * sB;
    const u16* planes3 = Bl + zb * sB;
    const int  pidx  = wv >> 1;
    const u16* psrc  = (pidx == 0) ? planes0 : (pidx == 1) ? planes1
                     : (pidx == 2) ? planes2 : planes3;
    const int  rbase = ((pidx < 2) ? bx : by) * 16 + (wv & 1) * 8;
    const int  r16n  = (pidx < 2) ? r16A : r16B;
    const int  dblk  = (pidx << 4) + ((wv & 1) << 3);   // LDS block base

    auto STAGE = [&](int buf, int s) {
        const u16* g = psrc + (((long)s * r16n + rbase) << 9) + lane * 8;
        u16* d = &sm[buf][dblk][0] + lane * 8;
        #pragma unroll
        for (int i = 0; i < 8; ++i)
            gld_lds16(g + (i << 9), d + (i << 9));
    };

    f32x4 acc[8][4];
    #pragma unroll
    for (int i = 0; i < 8; ++i)
        #pragma unroll
        for (int j = 0; j < 4; ++j)
            #pragma unroll
            for (int r = 0; r < 4; ++r) acc[i][j][r] = 0.f;

    STAGE(0, 0);
    int cur = 0;
    const int lo = lane * 8;

    for (int s = 0; s < nk32; ++s) {
        __syncthreads();                    // buf[cur] staged; prev reads drained
        if (s + 1 < nk32) STAGE(cur ^ 1, s + 1);   // latency hides under MFMA below

        // B fragments (held across both phases)
        short8 bfh[4], bfl[4];
        #pragma unroll
        for (int j = 0; j < 4; ++j) {
            bfh[j] = *(const short8*)&sm[cur][32 + wcn * 4 + j][lo];
            bfl[j] = *(const short8*)&sm[cur][48 + wcn * 4 + j][lo];
        }

        // phase 1: A rows 0..3
        {
            short8 afh[4], afl[4];
            #pragma unroll
            for (int i = 0; i < 4; ++i) {
                afh[i] = *(const short8*)&sm[cur][     wr * 8 + i][lo];
                afl[i] = *(const short8*)&sm[cur][16 + wr * 8 + i][lo];
            }
            __builtin_amdgcn_s_setprio(1);
            #pragma unroll
            for (int i = 0; i < 4; ++i)
                #pragma unroll
                for (int j = 0; j < 4; ++j)
                    mfma_triple(acc[i][j], afh[i], afl[i], bfh[j], bfl[j]);
            __builtin_amdgcn_s_setprio(0);
        }
        // phase 2: A rows 4..7
        {
            short8 afh[4], afl[4];
            #pragma unroll
            for (int i = 0; i < 4; ++i) {
                afh[i] = *(const short8*)&sm[cur][     wr * 8 + 4 + i][lo];
                afl[i] = *(const short8*)&sm[cur][16 + wr * 8 + 4 + i][lo];
            }
            __builtin_amdgcn_s_setprio(1);
            #pragma unroll
            for (int i = 0; i < 4; ++i)
                #pragma unroll
                for (int j = 0; j < 4; ++j)
                    mfma_triple(acc[4 + i][j], afh[i], afl[i], bfh[j], bfl[j]);
            __builtin_amdgcn_s_setprio(0);
        }
        cur ^= 1;
    }

    // C/D layout: col n = lane&15, row m = 4*(lane>>4)+reg
    const int m_ = lane & 15, q_ = lane >> 4;
    float* Cb = C + zb * sC;
    const int row00 = bx * 256 + wr * 128 + q_ * 4;
    const int col0  = by * 256 + wcn * 64 + m_;
    #pragma unroll
    for (int i = 0; i < 8; ++i)
        #pragma unroll
        for (int j = 0; j < 4; ++j) {
            const long base = (long)(row00 + i * 16) * ldc + col0 + j * 16;
            #pragma unroll
            for (int r = 0; r < 4; ++r)
                Cb[base + (long)r * ldc] = acc[i][j][r];
        }
}

// ---------------------------------------------------------------------------
// Depthwise causal conv4 + SiLU; emits x as split bf16 hi/lo planes (B,DI,L).
// ---------------------------------------------------------------------------
__global__ __launch_bounds__(256) void conv_silu_split(
    const float* __restrict__ xz, const float* __restrict__ conv_w,
    const float* __restrict__ conv_b,
    u16* __restrict__ xh_gl, u16* __restrict__ xl_gl)
{
    const long gid = (long)blockIdx.x * 256 + threadIdx.x;
    const int  q   = (int)(gid % (L_SZ / 4));
    const long bc  = gid / (L_SZ / 4);
    const int  ch  = (int)(bc % DI);
    const int  b   = (int)(bc / DI);

    const float* row = xz + ((long)b * E_SZ + ch) * L_SZ;
    const int l0 = q * 4;

    float4 cur  = *(const float4*)&row[l0];
    float4 prev = q ? *(const float4*)&row[l0 - 4] : make_float4(0.f, 0.f, 0.f, 0.f);

    const float w0 = conv_w[ch*DC+0], w1 = conv_w[ch*DC+1];
    const float w2 = conv_w[ch*DC+2], w3 = conv_w[ch*DC+3];
    const float bias = conv_b[ch];

    float o[4];
    o[0] = silu_f(bias + w0*prev.y + w1*prev.z + w2*prev.w + w3*cur.x);
    o[1] = silu_f(bias + w0*prev.z + w1*prev.w + w2*cur.x  + w3*cur.y);
    o[2] = silu_f(bias + w0*prev.w + w1*cur.x  + w2*cur.y  + w3*cur.z);
    o[3] = silu_f(bias + w0*cur.x  + w1*cur.y  + w2*cur.z  + w3*cur.w);

    unsigned long long hp = 0ull, lp = 0ull;
    #pragma unroll
    for (int r = 0; r < 4; ++r) {
        u16 h, l; split_bf16(o[r], h, l);
        hp |= ((unsigned long long)h) << (16*r);
        lp |= ((unsigned long long)l) << (16*r);
    }
    const long base = ((long)b * DI + ch) * L_SZ + l0;
    *(unsigned long long*)&xh_gl[base] = hp;
    *(unsigned long long*)&xl_gl[base] = lp;
}

// ---------------------------------------------------------------------------
// pack_k: k_ssm (DI, L) fp32 -> klv (DI, L) u32 with split-bf16 planes
// interleaved per element:  klv[i] = (u16)hi | ((u16)lo << 16).
// ---------------------------------------------------------------------------
__global__ __launch_bounds__(256) void pack_k(
    const float* __restrict__ k_ssm, unsigned* __restrict__ kv)
{
    const long gid = (long)blockIdx.x * 256 + threadIdx.x;   // DI*L/4 threads
    const int  qq  = (int)(gid & (L_SZ / 4 - 1));
    const int  ch  = (int)(gid >> 10);

    const long off = ((long)ch << 12) + qq * 4;
    float4 v = *(const float4*)&k_ssm[off];
    float f[4] = { v.x, v.y, v.z, v.w };
    unsigned o[4];
    #pragma unroll
    for (int r = 0; r < 4; ++r) {
        u16 h, l; split_bf16(f[r], h, l);
        o[r] = (unsigned)h | ((unsigned)l << 16);
    }
    *(uint4*)&kv[off] = *(const uint4*)o;
}

// ---------------------------------------------------------------------------
// MFMA long causal conv -- FROZEN R2 body (202.6us, VGPR 32, occupancy 70%,
// zero spill).  Five structural variants refuted on counters (R3-R7).
// Do not modify without new counter evidence.
// ---------------------------------------------------------------------------
__global__ __launch_bounds__(256, 6) void longconv_mfma(
    u16* __restrict__ xh_gl, u16* __restrict__ xl_gl,
    const float* __restrict__ xz,  const unsigned* __restrict__ kv,
    const float* __restrict__ D_skip)
{
    __shared__ alignas(16) u16 XH[4352];   // 256 zero-pad + 4096
    __shared__ alignas(16) u16 XL[4352];

    const int tid  = threadIdx.x;
    const int lane = tid & 63;
    const int wv   = tid >> 6;
    const int wc   = blockIdx.x;          // one channel per block
    const int ch   = wc & (DI - 1);
    const int b    = wc >> 11;

    u16*            xhr = xh_gl + ((long)b * DI + ch) * L_SZ;
    u16*            xlr = xl_gl + ((long)b * DI + ch) * L_SZ;
    const unsigned* kvr = kv + ((long)ch << 12);

    // zero the 512B pad of each plane (64 threads x 16B)
    if (tid < 64) {
        uint4 z = make_uint4(0u, 0u, 0u, 0u);
        ((uint4*)((tid < 32) ? XH : XL))[tid & 31] = z;
    }
    // async stage 8KB/plane: wave wv owns chunks {2wv, 2wv+1} of each plane
    {
        const int ck = wv * 2;
        gld_lds16(xhr + (ck    ) * 512 + lane * 8, XH + 256 + (ck    ) * 512);
        gld_lds16(xhr + (ck + 1) * 512 + lane * 8, XH + 256 + (ck + 1) * 512);
        gld_lds16(xlr + (ck    ) * 512 + lane * 8, XL + 256 + (ck    ) * 512);
        gld_lds16(xlr + (ck + 1) * 512 + lane * 8, XL + 256 + (ck + 1) * 512);
    }
    __syncthreads();

    const int m_ = lane & 15;
    const int q_ = lane >> 4;
    const int dq = m_ - 8 * q_ + ((q_ >= 2) ? 32 : 0);
    const int xoff_lane = 256 + 16 * m_ + 8 * q_ - ((q_ >= 2) ? 32 : 0);

    // balanced tile set for this wave: {w, 7-w, 8+w, 15-w}
    const int tset[4] = { wv, 7 - wv, 8 + wv, 15 - wv };
    const int tmax = 15 - wv;                 // largest tile owned
    const int cmax = 8 * tmax + 7;            // last c this wave needs

    f32x4 acc[4];
    #pragma unroll
    for (int u = 0; u < 4; ++u)
        #pragma unroll
        for (int r = 0; r < 4; ++r) acc[u][r] = 0.f;

    const unsigned* kp = kvr + dq;   // in-loop idx = 32*c1 + dq - e >= 17: safe

    unsigned lcur[8];
    #pragma unroll
    for (int e = 0; e < 8; ++e) {
        const int ki = dq - e;                        // -15..31: predicate once
        lcur[e] = (ki >= 0) ? kvr[ki] : 0u;
    }

    for (int c = 0; c <= cmax; ++c) {
        // assemble ah/al from interleaved dwords: 2 perms per pair
        short8 ah, al;
        kperm(lcur, ah, al);

        unsigned lnext[8];
        if (c < cmax) kpref(kp, c + 1, lnext);

        const int xbase = xoff_lane - 32 * c;
        #pragma unroll
        for (int u = 0; u < 4; ++u) {
            const int t = tset[u];
            if (8 * t >= c - 7) {
                short8 bh = *(const short8*)&XH[xbase + 256 * t];
                short8 bl = *(const short8*)&XL[xbase + 256 * t];
                acc[u] = __builtin_amdgcn_mfma_f32_16x16x32_bf16(ah, bh, acc[u], 0, 0, 0);
                acc[u] = __builtin_amdgcn_mfma_f32_16x16x32_bf16(ah, bl, acc[u], 0, 0, 0);
                acc[u] = __builtin_amdgcn_mfma_f32_16x16x32_bf16(al, bh, acc[u], 0, 0, 0);
            }
        }

        if (c < cmax) {
            #pragma unroll
            for (int e = 0; e < 8; ++e) lcur[e] = lnext[e];
        }
    }

    // epilogue: y = (conv + D_skip*x) * silu(z)  -> split bf16, in-place rows
    const float  Ds   = D_skip[ch];
    const float* zrow = xz + ((long)b * E_SZ + DI + ch) * L_SZ;

    #pragma unroll
    for (int u = 0; u < 4; ++u) {
        const int t  = tset[u];
        const int l0 = 256 * t + 16 * m_ + 4 * q_;
        float4 zv = *(const float4*)&zrow[l0];
        float zt[4] = { zv.x, zv.y, zv.z, zv.w };
        unsigned long long hp = 0ull, lp = 0ull;
        #pragma unroll
        for (int r = 0; r < 4; ++r) {
            const float xf = bf2f(XH[256 + l0 + r]) + bf2f(XL[256 + l0 + r]);
            const float o  = (acc[u][r] + Ds * xf) * silu_f(zt[r]);
            u16 h, l; split_bf16(o, h, l);
            hp |= ((unsigned long long)h) << (16*r);
            lp |= ((unsigned long long)l) << (16*r);
        }
        *(unsigned long long*)&xhr[l0] = hp;
        *(unsigned long long*)&xlr[l0] = lp;
    }
}

// ---------------------------------------------------------------------------
// pack_y: y split planes (B,DI,L) u16 -> GEMM2 A-operand fragment-blocked
// [K/32=64][L/16=256][512] per batch, via LDS transpose tile (32h x 128l).
// ---------------------------------------------------------------------------
__global__ __launch_bounds__(256) void pack_y(
    const u16* __restrict__ Yh, const u16* __restrict__ Yl,
    u16* __restrict__ OH, u16* __restrict__ OL, long sOut)
{
    __shared__ u16 T[2][32][136];
    const int t  = threadIdx.x;
    const int l0 = blockIdx.x * 128;
    const int h0 = blockIdx.y * 32;
    const int b  = blockIdx.z;

    const u16* yb_h = Yh + ((long)b * DI + h0) * L_SZ + l0;
    const u16* yb_l = Yl + ((long)b * DI + h0) * L_SZ + l0;

    #pragma unroll
    for (int i = 0; i < 2; ++i) {
        const int c = t + 256 * i;            // 0..511
        const int row = c >> 4, col = (c & 15) * 8;
        *(uint4*)&T[0][row][col] = *(const uint4*)&yb_h[(long)row * L_SZ + col];
        *(uint4*)&T[1][row][col] = *(const uint4*)&yb_l[(long)row * L_SZ + col];
    }
    __syncthreads();

    u16* outs[2] = { OH + b * sOut, OL + b * sOut };
    #pragma unroll
    for (int p = 0; p < 2; ++p) {
        #pragma unroll
        for (int i = 0; i < 2; ++i) {
            const int c = t + 256 * i;        // 0..511
            const int r16b = c >> 6, qc = c & 63;
            const int q = qc >> 4, m = qc & 15;
            const int l = r16b * 16 + m;
            u16 vals[8];
            #pragma unroll
            for (int j = 0; j < 8; ++j) vals[j] = T[p][q * 8 + j][l];
            const long o = ((long)(blockIdx.y * 256 + blockIdx.x * 8 + r16b) << 9) + qc * 8;
            *(uint4*)&outs[p][o] = *(const uint4*)vals;
        }
    }
}

// ---------------------------------------------------------------------------
extern "C" void kernel_launch(void* const* d_in, const int* in_sizes, int n_in,
                              void* d_out, int out_size, void* d_ws, size_t ws_size,
                              hipStream_t stream)
{
    const float* hidden = (const float*)d_in[0];  // (B, L, DM)
    const float* W_in   = (const float*)d_in[1];  // (E, DM)
    const float* conv_w = (const float*)d_in[2];  // (DI, 4)
    const float* conv_b = (const float*)d_in[3];  // (DI)
    const float* k_ssm  = (const float*)d_in[4];  // (DI, L)
    const float* D_skip = (const float*)d_in[5];  // (DI)
    const float* W_out  = (const float*)d_in[6];  // (DM, DI)
    float* out = (float*)d_out;                   // (B, L, DM)

    // ---- workspace layout (bytes) ----
    // xz fp32 (B,E,L)            @ 0          134,217,728
    //   klv u32 (DI,L) aliases xz x-half b=0 [0 .. 33,554,432) after conv
    // xh u16  (B,DI,L)           @ 134,217,728  33,554,432   (becomes y-hi)
    // xl u16  (B,DI,L)           @ 167,772,160  33,554,432   (becomes y-lo)
    // slotA: Win packs -> Wout packs @ 201,326,592  16,777,216
    // slotB: hidden packs        @ 218,103,808  33,554,432
    // yA packs alias xz x-halves (dead after longconv; overwrite klv too)
    char* ws = (char*)d_ws;
    float* xz  = (float*)ws;
    u16*   xh  = (u16*)(ws + 134217728);
    u16*   xl  = (u16*)(ws + 167772160);
    u16*   WinH  = (u16*)(ws + 201326592);
    u16*   WinL  = WinH + 4194304;            // 32*256*512
    u16*   WoutH = (u16*)(ws + 201326592);    // reused after GEMM1
    u16*   WoutL = WoutH + 2097152;           // 64*64*512
    u16*   hidH  = (u16*)(ws + 218103808);
    u16*   hidL  = hidH + 8388608;            // per-plane both batches
    unsigned* klv = (unsigned*)ws;            // aliases dead xz x-half b=0
    u16*   yAh   = (u16*)ws;                  // aliases xz; per-batch stride 33,554,432 elems
    u16*   yAl   = yAh + 8388608;

    // 1) pack W_in (R=E=4096,K=DM=1024) and hidden (per b: R=L,K=DM)
    pack_rm<<<dim3(2048, 1), 256, 0, stream>>>(W_in, WinH, WinL, DM, 256, 0L, 0L);
    pack_rm<<<dim3(2048, B_SZ), 256, 0, stream>>>(hidden, hidH, hidL, DM, 256,
        (long)L_SZ * DM, 4194304L);

    // 2) GEMM1: xz[b,e,l] = sum_d W_in[e,d]*hidden[b,l,d]  (256^2 pipelined)
    gemm256<<<dim3(16, 16, B_SZ), 512, 0, stream>>>(
        WinH, WinL, hidH, hidL, xz,
        256, 256, 0L, 4194304L, (long)E_SZ * L_SZ, L_SZ, 32);

    // 3) depthwise causal conv4 + SiLU -> split bf16 x
    conv_silu_split<<<dim3((unsigned)((long)B_SZ*DI*(L_SZ/4)/256)), 256, 0, stream>>>(
        xz, conv_w, conv_b, xh, xl);

    // 3b) pack k into interleaved split-bf16 dwords (xz x-half b0 now dead)
    pack_k<<<dim3((unsigned)((long)DI * (L_SZ/4) / 256)), 256, 0, stream>>>(k_ssm, klv);

    // 4) MFMA long causal conv + D_skip + silu(z) -> y split, in-place in xh/xl
    longconv_mfma<<<dim3(B_SZ * DI), 256, 0, stream>>>(
        xh, xl, xz, klv, D_skip);

    // 5) pack W_out (R=DM=1024,K=DI=2048) into slotA (Win packs now dead)
    pack_rm<<<dim3(1024, 1), 256, 0, stream>>>(W_out, WoutH, WoutL, DI, 64, 0L, 0L);

    // 6) pack y -> GEMM2 A-operand blocked (into dead xz x-half region)
    pack_y<<<dim3(32, 64, B_SZ), 256, 0, stream>>>(
        xh, xl, yAh, yAl, 33554432L);

    // 7) GEMM2: out[b,l,d] = sum_h y[b,h,l]*W_out[d,h]  (128^2, R2-exact)
    gemm_mfma<<<dim3(32, 8, B_SZ), 256, 0, stream>>>(
        yAh, yAl, WoutH, WoutL, out,
        256, 64, 33554432L, 0L, (long)L_SZ * DM, DM, 64);
}

// Round 10
// 621.916 us; speedup vs baseline: 1.2383x; 1.0063x over previous
//
#include <hip/hip_runtime.h>
#include <hip/hip_bf16.h>
#include <math.h>

// Problem constants: B,L,D_MODEL=(2,4096,1024), D_INNER=2048, D_CONV=4
#define B_SZ 2
#define L_SZ 4096
#define DM   1024
#define DI   2048
#define E_SZ 4096
#define DC   4

typedef unsigned short u16;
typedef __attribute__((ext_vector_type(8))) short short8;   // 8 bf16 = 4 VGPRs
typedef __attribute__((ext_vector_type(4))) float f32x4;

__device__ __forceinline__ float silu_f(float v) {
    return v / (1.0f + __expf(-v));
}

// split fp32 -> bf16 hi (truncate) + bf16 lo (truncate of exact residual)
__device__ __forceinline__ void split_bf16(float x, u16& h, u16& l) {
    unsigned u  = __float_as_uint(x);
    unsigned hb = u & 0xFFFF0000u;
    h = (u16)(hb >> 16);
    float lf = x - __uint_as_float(hb);
    l = (u16)(__float_as_uint(lf) >> 16);
}
__device__ __forceinline__ float bf2f(u16 h) {
    return __uint_as_float(((unsigned)h) << 16);
}

// async global->LDS 16B: dest = wave-uniform LDS base + lane*16
__device__ __forceinline__ void gld_lds16(const u16* g, u16* l) {
    __builtin_amdgcn_global_load_lds(
        (const __attribute__((address_space(1))) unsigned int*)g,
        (__attribute__((address_space(3))) unsigned int*)l, 16, 0, 0);
}

// build ah/al bf16x8 fragments from 8 interleaved (hi|lo) dwords
__device__ __forceinline__ void kperm(const unsigned* cur, short8& ah, short8& al) {
    union { unsigned u[4]; short8 s; } A_, B_;
    #pragma unroll
    for (int i = 0; i < 4; ++i) {
        A_.u[i] = __builtin_amdgcn_perm(cur[2*i+1], cur[2*i], 0x05040100u);
        B_.u[i] = __builtin_amdgcn_perm(cur[2*i+1], cur[2*i], 0x07060302u);
    }
    ah = A_.s; al = B_.s;
}
// prefetch k dwords for step c1 (indices provably >= 17 for c1 >= 1)
__device__ __forceinline__ void kpref(const unsigned* kp, int c1, unsigned* nxt) {
    #pragma unroll
    for (int e = 0; e < 8; ++e) nxt[e] = kp[32*c1 - e];
}

// ---------------------------------------------------------------------------
// pack_rm: fp32 row-major (R x K, k-contiguous, ldx) -> fragment-blocked split
// planes H/Lo laid out [K/32][R/16][512]; within a 16x32 block, element
// (m, k=8q+j) sits at (q*16+m)*8+j  == exactly the 16x16x32 MFMA frag order.
// ---------------------------------------------------------------------------
__global__ __launch_bounds__(256) void pack_rm(
    const float* __restrict__ X, u16* __restrict__ H, u16* __restrict__ Lo,
    int ldx, int r16n, long sX, long sOut)
{
    const long cid = (long)blockIdx.x * 256 + threadIdx.x;
    const int  qc  = (int)(cid & 63);
    const long blk = cid >> 6;
    const int  r16 = (int)(blk % r16n);
    const int  k32 = (int)(blk / r16n);
    const int  q = qc >> 4, m = qc & 15;

    const float* src = X + blockIdx.y * sX + (long)(r16 * 16 + m) * ldx + k32 * 32 + q * 8;
    float4 v0 = *(const float4*)src;
    float4 v1 = *(const float4*)(src + 4);
    float v[8] = {v0.x,v0.y,v0.z,v0.w,v1.x,v1.y,v1.z,v1.w};

    u16 hs[8], ls[8];
    #pragma unroll
    for (int j = 0; j < 8; ++j) split_bf16(v[j], hs[j], ls[j]);

    const long o = blockIdx.y * sOut + cid * 8;
    *(uint4*)&H[o]  = *(const uint4*)hs;
    *(uint4*)&Lo[o] = *(const uint4*)ls;
}

// ---------------------------------------------------------------------------
// MFMA split-bf16 GEMM, R2-exact: 128x128 tile, BK=32, 4 waves.  Used for
// BOTH GEMMs.  R9 evidence: 256^2 2-phase (1 block/CU, lockstep barrier)
// lands at parity -- inter-block overlap at 2-3 blocks/CU is what makes the
// 128^2 structure work (m114); the only faster schedule (8-phase counted
// vmcnt) needs 2x the LDS our split-bf16 operands allow.  Frozen.
// ---------------------------------------------------------------------------
__global__ __launch_bounds__(256) void gemm_mfma(
    const u16* __restrict__ Ah, const u16* __restrict__ Al,
    const u16* __restrict__ Bh, const u16* __restrict__ Bl,
    float* __restrict__ C,
    int r16A, int r16B, long sA, long sB, long sC,
    int ldc, int nk32)
{
    __shared__ alignas(16) u16 sm[4][4096];   // Ah,Al,Bh,Bl 128x32 tiles (8KB each)

    const int tid  = threadIdx.x;
    const int wv   = tid >> 6, lane = tid & 63;
    const long zb  = blockIdx.z;

    const u16* srcs0 = Ah + zb * sA;
    const u16* srcs1 = Al + zb * sA;
    const u16* srcs2 = Bh + zb * sB;
    const u16* srcs3 = Bl + zb * sB;
    const u16* mysrc = (wv == 0) ? srcs0 : (wv == 1) ? srcs1 : (wv == 2) ? srcs2 : srcs3;
    const int  rblk  = (wv < 2) ? blockIdx.x * 8 : blockIdx.y * 8;
    const int  r16c  = (wv < 2) ? r16A : r16B;
    u16* myl = sm[wv];

    const int wr = wv >> 1, wc = wv & 1;

    f32x4 acc[4][4];
    #pragma unroll
    for (int i = 0; i < 4; ++i)
        #pragma unroll
        for (int j = 0; j < 4; ++j)
            #pragma unroll
            for (int r = 0; r < 4; ++r) acc[i][j][r] = 0.f;

    for (int s = 0; s < nk32; ++s) {
        if (s) __syncthreads();
        {
            const u16* g = mysrc + (((long)s * r16c + rblk) << 9) + lane * 8;
            #pragma unroll
            for (int i = 0; i < 8; ++i)
                gld_lds16(g + (i << 9), myl + (i << 9));
        }
        __syncthreads();

        short8 afh[4], afl[4], bfh[4], bfl[4];
        const int aoff = (wr * 4) * 512 + lane * 8;
        const int boff = (wc * 4) * 512 + lane * 8;
        #pragma unroll
        for (int t = 0; t < 4; ++t) {
            afh[t] = *(const short8*)&sm[0][aoff + t * 512];
            afl[t] = *(const short8*)&sm[1][aoff + t * 512];
            bfh[t] = *(const short8*)&sm[2][boff + t * 512];
            bfl[t] = *(const short8*)&sm[3][boff + t * 512];
        }
        #pragma unroll
        for (int i = 0; i < 4; ++i)
            #pragma unroll
            for (int j = 0; j < 4; ++j) {
                acc[i][j] = __builtin_amdgcn_mfma_f32_16x16x32_bf16(afh[i], bfh[j], acc[i][j], 0, 0, 0);
                acc[i][j] = __builtin_amdgcn_mfma_f32_16x16x32_bf16(afh[i], bfl[j], acc[i][j], 0, 0, 0);
                acc[i][j] = __builtin_amdgcn_mfma_f32_16x16x32_bf16(afl[i], bfh[j], acc[i][j], 0, 0, 0);
            }
    }

    // C/D layout: col n = lane&15, row m = 4*(lane>>4)+reg
    const int m_ = lane & 15, q_ = lane >> 4;
    float* Cb = C + zb * sC;
    const int row00 = blockIdx.x * 128 + wr * 64 + q_ * 4;
    const int col0  = blockIdx.y * 128 + wc * 64 + m_;
    #pragma unroll
    for (int i = 0; i < 4; ++i)
        #pragma unroll
        for (int j = 0; j < 4; ++j) {
            const long base = (long)(row00 + i * 16) * ldc + col0 + j * 16;
            #pragma unroll
            for (int r = 0; r < 4; ++r)
                Cb[base + (long)r * ldc] = acc[i][j][r];
        }
}

// ---------------------------------------------------------------------------
// Depthwise causal conv4 + SiLU; emits x as split bf16 hi/lo planes (B,DI,L).
// ---------------------------------------------------------------------------
__global__ __launch_bounds__(256) void conv_silu_split(
    const float* __restrict__ xz, const float* __restrict__ conv_w,
    const float* __restrict__ conv_b,
    u16* __restrict__ xh_gl, u16* __restrict__ xl_gl)
{
    const long gid = (long)blockIdx.x * 256 + threadIdx.x;
    const int  q   = (int)(gid % (L_SZ / 4));
    const long bc  = gid / (L_SZ / 4);
    const int  ch  = (int)(bc % DI);
    const int  b   = (int)(bc / DI);

    const float* row = xz + ((long)b * E_SZ + ch) * L_SZ;
    const int l0 = q * 4;

    float4 cur  = *(const float4*)&row[l0];
    float4 prev = q ? *(const float4*)&row[l0 - 4] : make_float4(0.f, 0.f, 0.f, 0.f);

    const float w0 = conv_w[ch*DC+0], w1 = conv_w[ch*DC+1];
    const float w2 = conv_w[ch*DC+2], w3 = conv_w[ch*DC+3];
    const float bias = conv_b[ch];

    float o[4];
    o[0] = silu_f(bias + w0*prev.y + w1*prev.z + w2*prev.w + w3*cur.x);
    o[1] = silu_f(bias + w0*prev.z + w1*prev.w + w2*cur.x  + w3*cur.y);
    o[2] = silu_f(bias + w0*prev.w + w1*cur.x  + w2*cur.y  + w3*cur.z);
    o[3] = silu_f(bias + w0*cur.x  + w1*cur.y  + w2*cur.z  + w3*cur.w);

    unsigned long long hp = 0ull, lp = 0ull;
    #pragma unroll
    for (int r = 0; r < 4; ++r) {
        u16 h, l; split_bf16(o[r], h, l);
        hp |= ((unsigned long long)h) << (16*r);
        lp |= ((unsigned long long)l) << (16*r);
    }
    const long base = ((long)b * DI + ch) * L_SZ + l0;
    *(unsigned long long*)&xh_gl[base] = hp;
    *(unsigned long long*)&xl_gl[base] = lp;
}

// ---------------------------------------------------------------------------
// pack_k: k_ssm (DI, L) fp32 -> klv (DI, L) u32 with split-bf16 planes
// interleaved per element:  klv[i] = (u16)hi | ((u16)lo << 16).
// NOTE: klv aliases the dead xz x-half (b=0) -- must run AFTER conv_silu_split
// (fusing the two would be a read/write race on that region).
// ---------------------------------------------------------------------------
__global__ __launch_bounds__(256) void pack_k(
    const float* __restrict__ k_ssm, unsigned* __restrict__ kv)
{
    const long gid = (long)blockIdx.x * 256 + threadIdx.x;   // DI*L/4 threads
    const int  qq  = (int)(gid & (L_SZ / 4 - 1));
    const int  ch  = (int)(gid >> 10);

    const long off = ((long)ch << 12) + qq * 4;
    float4 v = *(const float4*)&k_ssm[off];
    float f[4] = { v.x, v.y, v.z, v.w };
    unsigned o[4];
    #pragma unroll
    for (int r = 0; r < 4; ++r) {
        u16 h, l; split_bf16(f[r], h, l);
        o[r] = (unsigned)h | ((unsigned)l << 16);
    }
    *(uint4*)&kv[off] = *(const uint4*)o;
}

// ---------------------------------------------------------------------------
// MFMA long causal conv -- FROZEN R2 body (202.6us, VGPR 32, occupancy ~70%,
// zero spill).  Five structural variants refuted on counters:
//  R3/R4 reg-ring: spilled under launch_bounds VGPR brackets (+550/77MB HBM)
//  R5 ring @ (256,1): clean regs but 21% occupancy -> latency-bound (325us)
//  R6 segmented guard-free loop: regalloc perturbation, minor spill (231us)
//  R7 bl via global: per-lane L2-latency on critical path (375us)
// Do not modify without new counter evidence.
// ---------------------------------------------------------------------------
__global__ __launch_bounds__(256, 6) void longconv_mfma(
    u16* __restrict__ xh_gl, u16* __restrict__ xl_gl,
    const float* __restrict__ xz,  const unsigned* __restrict__ kv,
    const float* __restrict__ D_skip)
{
    __shared__ alignas(16) u16 XH[4352];   // 256 zero-pad + 4096
    __shared__ alignas(16) u16 XL[4352];

    const int tid  = threadIdx.x;
    const int lane = tid & 63;
    const int wv   = tid >> 6;
    const int wc   = blockIdx.x;          // one channel per block
    const int ch   = wc & (DI - 1);
    const int b    = wc >> 11;

    u16*            xhr = xh_gl + ((long)b * DI + ch) * L_SZ;
    u16*            xlr = xl_gl + ((long)b * DI + ch) * L_SZ;
    const unsigned* kvr = kv + ((long)ch << 12);

    // zero the 512B pad of each plane (64 threads x 16B)
    if (tid < 64) {
        uint4 z = make_uint4(0u, 0u, 0u, 0u);
        ((uint4*)((tid < 32) ? XH : XL))[tid & 31] = z;
    }
    // async stage 8KB/plane: wave wv owns chunks {2wv, 2wv+1} of each plane
    {
        const int ck = wv * 2;
        gld_lds16(xhr + (ck    ) * 512 + lane * 8, XH + 256 + (ck    ) * 512);
        gld_lds16(xhr + (ck + 1) * 512 + lane * 8, XH + 256 + (ck + 1) * 512);
        gld_lds16(xlr + (ck    ) * 512 + lane * 8, XL + 256 + (ck    ) * 512);
        gld_lds16(xlr + (ck + 1) * 512 + lane * 8, XL + 256 + (ck + 1) * 512);
    }
    __syncthreads();

    const int m_ = lane & 15;
    const int q_ = lane >> 4;
    const int dq = m_ - 8 * q_ + ((q_ >= 2) ? 32 : 0);
    const int xoff_lane = 256 + 16 * m_ + 8 * q_ - ((q_ >= 2) ? 32 : 0);

    // balanced tile set for this wave: {w, 7-w, 8+w, 15-w}
    const int tset[4] = { wv, 7 - wv, 8 + wv, 15 - wv };
    const int tmax = 15 - wv;                 // largest tile owned
    const int cmax = 8 * tmax + 7;            // last c this wave needs

    f32x4 acc[4];
    #pragma unroll
    for (int u = 0; u < 4; ++u)
        #pragma unroll
        for (int r = 0; r < 4; ++r) acc[u][r] = 0.f;

    const unsigned* kp = kvr + dq;   // in-loop idx = 32*c1 + dq - e >= 17: safe

    unsigned lcur[8];
    #pragma unroll
    for (int e = 0; e < 8; ++e) {
        const int ki = dq - e;                        // -15..31: predicate once
        lcur[e] = (ki >= 0) ? kvr[ki] : 0u;
    }

    for (int c = 0; c <= cmax; ++c) {
        // assemble ah/al from interleaved dwords: 2 perms per pair
        short8 ah, al;
        kperm(lcur, ah, al);

        unsigned lnext[8];
        if (c < cmax) kpref(kp, c + 1, lnext);

        const int xbase = xoff_lane - 32 * c;
        #pragma unroll
        for (int u = 0; u < 4; ++u) {
            const int t = tset[u];
            if (8 * t >= c - 7) {
                short8 bh = *(const short8*)&XH[xbase + 256 * t];
                short8 bl = *(const short8*)&XL[xbase + 256 * t];
                acc[u] = __builtin_amdgcn_mfma_f32_16x16x32_bf16(ah, bh, acc[u], 0, 0, 0);
                acc[u] = __builtin_amdgcn_mfma_f32_16x16x32_bf16(ah, bl, acc[u], 0, 0, 0);
                acc[u] = __builtin_amdgcn_mfma_f32_16x16x32_bf16(al, bh, acc[u], 0, 0, 0);
            }
        }

        if (c < cmax) {
            #pragma unroll
            for (int e = 0; e < 8; ++e) lcur[e] = lnext[e];
        }
    }

    // epilogue: y = (conv + D_skip*x) * silu(z)  -> split bf16, in-place rows
    const float  Ds   = D_skip[ch];
    const float* zrow = xz + ((long)b * E_SZ + DI + ch) * L_SZ;

    #pragma unroll
    for (int u = 0; u < 4; ++u) {
        const int t  = tset[u];
        const int l0 = 256 * t + 16 * m_ + 4 * q_;
        float4 zv = *(const float4*)&zrow[l0];
        float zt[4] = { zv.x, zv.y, zv.z, zv.w };
        unsigned long long hp = 0ull, lp = 0ull;
        #pragma unroll
        for (int r = 0; r < 4; ++r) {
            const float xf = bf2f(XH[256 + l0 + r]) + bf2f(XL[256 + l0 + r]);
            const float o  = (acc[u][r] + Ds * xf) * silu_f(zt[r]);
            u16 h, l; split_bf16(o, h, l);
            hp |= ((unsigned long long)h) << (16*r);
            lp |= ((unsigned long long)l) << (16*r);
        }
        *(unsigned long long*)&xhr[l0] = hp;
        *(unsigned long long*)&xlr[l0] = lp;
    }
}

// ---------------------------------------------------------------------------
// pack_y: y split planes (B,DI,L) u16 -> GEMM2 A-operand fragment-blocked
// [K/32=64][L/16=256][512] per batch, via LDS transpose tile (32h x 128l).
// ---------------------------------------------------------------------------
__global__ __launch_bounds__(256) void pack_y(
    const u16* __restrict__ Yh, const u16* __restrict__ Yl,
    u16* __restrict__ OH, u16* __restrict__ OL, long sOut)
{
    __shared__ u16 T[2][32][136];
    const int t  = threadIdx.x;
    const int l0 = blockIdx.x * 128;
    const int h0 = blockIdx.y * 32;
    const int b  = blockIdx.z;

    const u16* yb_h = Yh + ((long)b * DI + h0) * L_SZ + l0;
    const u16* yb_l = Yl + ((long)b * DI + h0) * L_SZ + l0;

    #pragma unroll
    for (int i = 0; i < 2; ++i) {
        const int c = t + 256 * i;            // 0..511
        const int row = c >> 4, col = (c & 15) * 8;
        *(uint4*)&T[0][row][col] = *(const uint4*)&yb_h[(long)row * L_SZ + col];
        *(uint4*)&T[1][row][col] = *(const uint4*)&yb_l[(long)row * L_SZ + col];
    }
    __syncthreads();

    u16* outs[2] = { OH + b * sOut, OL + b * sOut };
    #pragma unroll
    for (int p = 0; p < 2; ++p) {
        #pragma unroll
        for (int i = 0; i < 2; ++i) {
            const int c = t + 256 * i;        // 0..511
            const int r16b = c >> 6, qc = c & 63;
            const int q = qc >> 4, m = qc & 15;
            const int l = r16b * 16 + m;
            u16 vals[8];
            #pragma unroll
            for (int j = 0; j < 8; ++j) vals[j] = T[p][q * 8 + j][l];
            const long o = ((long)(blockIdx.y * 256 + blockIdx.x * 8 + r16b) << 9) + qc * 8;
            *(uint4*)&outs[p][o] = *(const uint4*)vals;
        }
    }
}

// ---------------------------------------------------------------------------
extern "C" void kernel_launch(void* const* d_in, const int* in_sizes, int n_in,
                              void* d_out, int out_size, void* d_ws, size_t ws_size,
                              hipStream_t stream)
{
    const float* hidden = (const float*)d_in[0];  // (B, L, DM)
    const float* W_in   = (const float*)d_in[1];  // (E, DM)
    const float* conv_w = (const float*)d_in[2];  // (DI, 4)
    const float* conv_b = (const float*)d_in[3];  // (DI)
    const float* k_ssm  = (const float*)d_in[4];  // (DI, L)
    const float* D_skip = (const float*)d_in[5];  // (DI)
    const float* W_out  = (const float*)d_in[6];  // (DM, DI)
    float* out = (float*)d_out;                   // (B, L, DM)

    // ---- workspace layout (bytes) ----
    // xz fp32 (B,E,L)            @ 0          134,217,728
    //   klv u32 (DI,L) aliases xz x-half b=0 [0 .. 33,554,432) after conv
    // xh u16  (B,DI,L)           @ 134,217,728  33,554,432   (becomes y-hi)
    // xl u16  (B,DI,L)           @ 167,772,160  33,554,432   (becomes y-lo)
    // slotA: Win packs -> Wout packs @ 201,326,592  16,777,216
    // slotB: hidden packs        @ 218,103,808  33,554,432
    // yA packs alias xz x-halves (dead after longconv; overwrite klv too)
    char* ws = (char*)d_ws;
    float* xz  = (float*)ws;
    u16*   xh  = (u16*)(ws + 134217728);
    u16*   xl  = (u16*)(ws + 167772160);
    u16*   WinH  = (u16*)(ws + 201326592);
    u16*   WinL  = WinH + 4194304;            // 32*256*512
    u16*   WoutH = (u16*)(ws + 201326592);    // reused after GEMM1
    u16*   WoutL = WoutH + 2097152;           // 64*64*512
    u16*   hidH  = (u16*)(ws + 218103808);
    u16*   hidL  = hidH + 8388608;            // per-plane both batches
    unsigned* klv = (unsigned*)ws;            // aliases dead xz x-half b=0
    u16*   yAh   = (u16*)ws;                  // aliases xz; per-batch stride 33,554,432 elems
    u16*   yAl   = yAh + 8388608;

    // 1) pack W_in (R=E=4096,K=DM=1024) and hidden (per b: R=L,K=DM)
    pack_rm<<<dim3(2048, 1), 256, 0, stream>>>(W_in, WinH, WinL, DM, 256, 0L, 0L);
    pack_rm<<<dim3(2048, B_SZ), 256, 0, stream>>>(hidden, hidH, hidL, DM, 256,
        (long)L_SZ * DM, 4194304L);

    // 2) GEMM1: xz[b,e,l] = sum_d W_in[e,d]*hidden[b,l,d]
    gemm_mfma<<<dim3(32, 32, B_SZ), 256, 0, stream>>>(
        WinH, WinL, hidH, hidL, xz,
        256, 256, 0L, 4194304L, (long)E_SZ * L_SZ, L_SZ, 32);

    // 3) depthwise causal conv4 + SiLU -> split bf16 x
    conv_silu_split<<<dim3((unsigned)((long)B_SZ*DI*(L_SZ/4)/256)), 256, 0, stream>>>(
        xz, conv_w, conv_b, xh, xl);

    // 3b) pack k into interleaved split-bf16 dwords (xz x-half b0 now dead)
    pack_k<<<dim3((unsigned)((long)DI * (L_SZ/4) / 256)), 256, 0, stream>>>(k_ssm, klv);

    // 4) MFMA long causal conv + D_skip + silu(z) -> y split, in-place in xh/xl
    longconv_mfma<<<dim3(B_SZ * DI), 256, 0, stream>>>(
        xh, xl, xz, klv, D_skip);

    // 5) pack W_out (R=DM=1024,K=DI=2048) into slotA (Win packs now dead)
    pack_rm<<<dim3(1024, 1), 256, 0, stream>>>(W_out, WoutH, WoutL, DI, 64, 0L, 0L);

    // 6) pack y -> GEMM2 A-operand blocked (into dead xz x-half region)
    pack_y<<<dim3(32, 64, B_SZ), 256, 0, stream>>>(
        xh, xl, yAh, yAl, 33554432L);

    // 7) GEMM2: out[b,l,d] = sum_h y[b,h,l]*W_out[d,h]
    gemm_mfma<<<dim3(32, 8, B_SZ), 256, 0, stream>>>(
        yAh, yAl, WoutH, WoutL, out,
        256, 64, 33554432L, 0L, (long)L_SZ * DM, DM, 64);
}